// Round 15
// baseline (931.198 us; speedup 1.0000x reference)
//
#include <hip/hip_runtime.h>

#define NRAYS 2048
// X stored in MFMA-fragment order: tile (m=row/16, kt=col/32) at ((m*8+kt)*512),
// within tile: lane-chunk (q=col%32/8)*16 + (r=row%16), 8 f16 per chunk (col%8).
#define XTILE(m,kt) ((((m)<<3)+(kt))<<9)
__device__ __forceinline__ int xaddr(int row, int col){
  return XTILE(row>>4, col>>5) + ((((col&31)>>3)<<4) + (row&15))*8 + (col&7);
}

typedef _Float16 f16;
typedef __attribute__((ext_vector_type(4))) _Float16 f16x4;
typedef __attribute__((ext_vector_type(8))) _Float16 f16x8;
typedef __attribute__((ext_vector_type(4))) float f32x4;

__device__ __forceinline__ float sigmoidf(float x){ return 1.f/(1.f+expf(-x)); }

__device__ __forceinline__ float approx_cdf_f(float x){
  return 0.5f*(1.f + tanhf(0.7978845608028654f*(x + 0.044715f*x*x*x)));
}

// Giles (2010) single-precision erfinv, max rel err ~1e-6
__device__ __forceinline__ float erfinvf_dev(float x){
  float w = -logf((1.0f-x)*(1.0f+x));
  float p;
  if (w < 5.0f){
    w -= 2.5f;
    p = 2.81022636e-08f;
    p = fmaf(p,w, 3.43273939e-07f);
    p = fmaf(p,w,-3.5233877e-06f);
    p = fmaf(p,w,-4.39150654e-06f);
    p = fmaf(p,w, 0.00021858087f);
    p = fmaf(p,w,-0.00125372503f);
    p = fmaf(p,w,-0.00417768164f);
    p = fmaf(p,w, 0.246640727f);
    p = fmaf(p,w, 1.50140941f);
  } else {
    w = sqrtf(w) - 3.0f;
    p = -0.000200214257f;
    p = fmaf(p,w, 0.000100950558f);
    p = fmaf(p,w, 0.00134934322f);
    p = fmaf(p,w,-0.00367342844f);
    p = fmaf(p,w, 0.00573950773f);
    p = fmaf(p,w,-0.0076224613f);
    p = fmaf(p,w, 0.00943887047f);
    p = fmaf(p,w, 1.00167406f);
    p = fmaf(p,w, 2.83297682f);
  }
  return p*x;
}

// ---------- weight convert+transpose+split: W[Ksrc][N] f32 -> Wh/Wl[N][Kdst] f16 ----------
__global__ void k_cvtT(const float* __restrict__ W, f16* __restrict__ Wh, f16* __restrict__ Wl,
                       int Ksrc, int N, int Kdst){
  int g = blockIdx.x*blockDim.x + threadIdx.x;
  if (g >= N*Kdst) return;
  int n = g / Kdst, k = g - n*Kdst;
  float v = (k < Ksrc) ? W[(size_t)k*N + n] : 0.f;
  f16 h = (f16)v;
  Wh[g] = h;
  Wl[g] = (f16)(v - (float)h);
}

struct Weights {
  const f16 *W0h,*W0l; const float *b0;
  const f16 *Whh,*Whl; const float *bh;
  const float *Ws,*bs,*Wm,*bm;      // Wm,bm only used by coarse
  const f16 *Wbh,*Wbl; const float *bb;
  const f16 *Wdh,*Wdl; const float *Wdfull,*bd;
  const float *Wr,*br;
};

// One layer: X(128 x K, fragment-order LDS) @ BT^T (N=256 x K, L2) -> X.
// 16 waves; wave covers 16 output cols; 8 m-tiles -> acc[8].
// PF = B-prefetch depth (1 or 2) — load scheduling only, math identical.
// TRANSPOSED MFMA: acc = mfma(Bfrag, Afrag) = C^T; lane (q,r) holds row m*16+r,
// cols nbase+q*4..+3 -> single b64 write into fragment layout.
// SPLIT: acc = Bh*Ah + Bl*Ah + Bh*Al (fp32-equivalent), writes h+l.
// !SPLIT: acc = Bh*Ah (pure f16), reads/writes h only.
template<int K, bool SPLIT, int PF>
__device__ __forceinline__ void mlp_layer(
    f16* __restrict__ Xh, f16* __restrict__ Xl,
    const f16* __restrict__ Bh, const f16* __restrict__ Bl,
    const float* __restrict__ bias, const float* dctr, int relu,
    int wave, int q, int r, int lane)
{
  const int nbase = wave * 16;
  f32x4 acc[8];
  #pragma unroll
  for (int m=0;m<8;m++) acc[m] = (f32x4){0.f,0.f,0.f,0.f};
  {
    const f16* bhp = Bh + (size_t)(nbase + r)*K + q*8;
    const f16* blp = Bl + (size_t)(nbase + r)*K + q*8;
    f16x8 bhA = *(const f16x8*)bhp;
    f16x8 blA; if (SPLIT) blA = *(const f16x8*)blp;
    f16x8 bhB, blB;
    if (PF==2 && K>32){
      bhB = *(const f16x8*)(bhp + 32);
      if (SPLIT) blB = *(const f16x8*)(blp + 32);
    }
    #pragma unroll
    for (int k0=0;k0<K;k0+=32){
      const int kt = k0 >> 5;
      f16x8 bh_n, bl_n;
      if (k0 + 32*PF < K){
        bh_n = *(const f16x8*)(bhp + k0 + 32*PF);
        if (SPLIT) bl_n = *(const f16x8*)(blp + k0 + 32*PF);
      }
      #pragma unroll
      for (int m=0;m<8;m++){
        int ao = XTILE(m,kt) + (lane<<3);
        f16x8 ah = *(const f16x8*)&Xh[ao];
        acc[m] = __builtin_amdgcn_mfma_f32_16x16x32_f16(bhA, ah, acc[m], 0,0,0);
        if (SPLIT){
          f16x8 al = *(const f16x8*)&Xl[ao];
          acc[m] = __builtin_amdgcn_mfma_f32_16x16x32_f16(blA, ah, acc[m], 0,0,0);
          acc[m] = __builtin_amdgcn_mfma_f32_16x16x32_f16(bhA, al, acc[m], 0,0,0);
        }
      }
      if (PF==2){
        bhA = bhB; bhB = bh_n;
        if (SPLIT){ blA = blB; blB = bl_n; }
      } else {
        bhA = bh_n;
        if (SPLIT) blA = bl_n;
      }
    }
  }
  __syncthreads();   // all waves done reading X
  {
    const int c0 = nbase + q*4;
    const int ktp = c0 >> 5, qp = (c0 & 31) >> 3, j0 = c0 & 7;
    float ba0=0.f,ba1=0.f,ba2=0.f,ba3=0.f;
    if (bias){ ba0=bias[c0]; ba1=bias[c0+1]; ba2=bias[c0+2]; ba3=bias[c0+3]; }
    if (dctr){ ba0+=dctr[c0]; ba1+=dctr[c0+1]; ba2+=dctr[c0+2]; ba3+=dctr[c0+3]; }
    #pragma unroll
    for (int m=0;m<8;m++){
      int ao = XTILE(m,ktp) + ((qp<<4) + r)*8 + j0;
      float v0 = acc[m][0] + ba0, v1 = acc[m][1] + ba1;
      float v2 = acc[m][2] + ba2, v3 = acc[m][3] + ba3;
      if (relu){ v0=fmaxf(v0,0.f); v1=fmaxf(v1,0.f); v2=fmaxf(v2,0.f); v3=fmaxf(v3,0.f); }
      f16 h0=(f16)v0, h1=(f16)v1, h2=(f16)v2, h3=(f16)v3;
      f16x4 hv = {h0,h1,h2,h3};
      *(f16x4*)&Xh[ao] = hv;
      if (SPLIT){
        f16x4 lv = {(f16)(v0-(float)h0),(f16)(v1-(float)h1),(f16)(v2-(float)h2),(f16)(v3-(float)h3)};
        *(f16x4*)&Xl[ao] = lv;
      }
    }
  }
  __syncthreads();
}

// Wd layer variant: N=128 output cols, ALL 16 waves active:
// cg = wave&7 -> 16 cols; mh = wave>>3 -> m-tiles mh*4..mh*4+3 (acc[4]).
template<int K, int PF>
__device__ __forceinline__ void mlp_layer128(
    f16* __restrict__ Xh,
    const f16* __restrict__ Bh, const f16* __restrict__ Bl,
    const float* dctr, int wave, int q, int r, int lane)
{
  const int nbase = (wave & 7) * 16;
  const int mbase = (wave >> 3) * 4;
  f32x4 acc[4];
  #pragma unroll
  for (int m=0;m<4;m++) acc[m] = (f32x4){0.f,0.f,0.f,0.f};
  {
    const f16* bhp = Bh + (size_t)(nbase + r)*K + q*8;
    f16x8 bhA = *(const f16x8*)bhp;
    f16x8 bhB;
    if (PF==2 && K>32) bhB = *(const f16x8*)(bhp + 32);
    #pragma unroll
    for (int k0=0;k0<K;k0+=32){
      const int kt = k0 >> 5;
      f16x8 bh_n;
      if (k0 + 32*PF < K) bh_n = *(const f16x8*)(bhp + k0 + 32*PF);
      #pragma unroll
      for (int m=0;m<4;m++){
        int ao = XTILE(mbase+m,kt) + (lane<<3);
        f16x8 ah = *(const f16x8*)&Xh[ao];
        acc[m] = __builtin_amdgcn_mfma_f32_16x16x32_f16(bhA, ah, acc[m], 0,0,0);
      }
      if (PF==2){ bhA = bhB; bhB = bh_n; }
      else bhA = bh_n;
    }
  }
  __syncthreads();
  {
    const int c0 = nbase + q*4;
    const int ktp = c0 >> 5, qp = (c0 & 31) >> 3, j0 = c0 & 7;
    float ba0=dctr[c0], ba1=dctr[c0+1], ba2=dctr[c0+2], ba3=dctr[c0+3];
    #pragma unroll
    for (int m=0;m<4;m++){
      int ao = XTILE(mbase+m,ktp) + ((qp<<4) + r)*8 + j0;
      float v0 = fmaxf(acc[m][0] + ba0, 0.f), v1 = fmaxf(acc[m][1] + ba1, 0.f);
      float v2 = fmaxf(acc[m][2] + ba2, 0.f), v3 = fmaxf(acc[m][3] + ba3, 0.f);
      f16x4 hv = {(f16)v0,(f16)v1,(f16)v2,(f16)v3};
      *(f16x4*)&Xh[ao] = hv;
    }
  }
  __syncthreads();
}

// shared enc math
__device__ __forceinline__ void enc_vals(
    float t0, float t1, float rrv,
    const float* rov, const float* rdv, float invdd,
    int j, int kk, float& a0, float& a1)
{
  float c = 0.5f*(t0+t1), d = 0.5f*(t1-t0);
  float c2 = c*c, d2 = d*d;
  float denom = 3.f*c2 + d2;
  float t_mean = c + 2.f*c*d2/denom;
  float d4 = d2*d2;
  float t_var = d2*(1.f/3.f) - (4.f/15.f)*(d4*(12.f*c2 - d2))/(denom*denom);
  float r_var = rrv*rrv*(c2*0.25f + (5.f/12.f)*d2 - (4.f/15.f)*d4/denom);
  float mean = rov[j] + rdv[j]*t_mean;
  float doj = rdv[j]*rdv[j];
  float cov = t_var*doj + r_var*(1.f - doj*invdd);
  float sc = (float)(1<<kk);
  float att = expf(-0.5f*cov*sc*sc);
  float sv, cv;
  sincosf(mean*sc, &sv, &cv);
  a0 = sv*att; a1 = cv*att;
}

// ---------- COARSE: enc + exact trunk + heads + lite rgb-path + render + sampling ----------
__global__ __launch_bounds__(1024,4) void k_coarse(
    const float* __restrict__ ro, const float* __restrict__ rd, const float* __restrict__ rr,
    Weights w, float* __restrict__ tfine_out, float* __restrict__ dout)
{
  __shared__ f16 Xh[32768];
  __shared__ f16 Xl[32768];
  __shared__ float sh_de[32];
  __shared__ float sh_dctr[128];
  __shared__ float sh_sig[128], sh_mu[128], sh_sgm[128];
  __shared__ float sh_rgb[3*128];
  __shared__ float red[16];
  __shared__ float sh_w[128], sh_pdf[128], sh_cdf[132], sh_lt[128], sh_pib[128];
  __shared__ float s_wsum;

  int ray = blockIdx.x, tid = threadIdx.x;
  int wave = tid>>6, lane = tid&63, q = lane>>4, r = lane&15;

  float rdx = rd[ray*3], rdy = rd[ray*3+1], rdz = rd[ray*3+2];
  float rn = sqrtf(rdx*rdx+rdy*rdy+rdz*rdz);

  if (tid < 27){
    float v0=rdx/rn, v1=rdy/rn, v2=rdz/rn;
    float vv[3] = {v0,v1,v2};
    float o;
    if (tid < 3) o = vv[tid];
    else if (tid < 15){ int f=(tid-3)/3, j=(tid-3)%3; o = sinf(vv[j]*(float)(1<<f)); }
    else            { int f=(tid-15)/3, j=(tid-15)%3; o = cosf(vv[j]*(float)(1<<f)); }
    sh_de[tid] = o;
  }

  // enc (h+l): sample s = tid>>3, part p = tid&7 handles freqs p*2..p*2+1
  {
    int s = tid >> 3, p = tid & 7;
    float t0 = 2.f + 0.03125f*(float)s, t1 = t0 + 0.03125f;
    float rrv = rr[ray];
    float rdv[3] = {rdx, rdy, rdz};
    float rov[3] = {ro[ray*3], ro[ray*3+1], ro[ray*3+2]};
    float dd = rdx*rdx+rdy*rdy+rdz*rdz;
    float invdd = 1.f/fmaxf(dd, 1e-10f);
    #pragma unroll
    for (int j=0;j<3;j++){
      #pragma unroll
      for (int kk=p*2; kk<p*2+2; kk++){
        float a0, a1;
        enc_vals(t0,t1,rrv,rov,rdv,invdd,j,kk,a0,a1);
        f16 h0=(f16)a0, h1=(f16)a1;
        int i0 = xaddr(s, kk*3 + j), i1 = xaddr(s, 48 + kk*3 + j);
        Xh[i0]=h0; Xl[i0]=(f16)(a0-(float)h0);
        Xh[i1]=h1; Xl[i1]=(f16)(a1-(float)h1);
      }
    }
    #pragma unroll
    for (int i=0;i<4;i++){
      int a = xaddr(s, 96 + p*4 + i);
      Xh[a]=(f16)0.f; Xl[a]=(f16)0.f;
    }
  }
  __syncthreads();

  if (tid < 128){
    float acc = w.bd[tid];
    #pragma unroll
    for (int k=0;k<27;k++) acc = fmaf(sh_de[k], w.Wdfull[(size_t)(256+k)*128 + tid], acc);
    sh_dctr[tid] = acc;
  }

  // ---- exact trunk (feeds the chaotic sampler) ----
  mlp_layer<128,true,2>(Xh,Xl, w.W0h, w.W0l, w.b0, nullptr, 1, wave,q,r,lane);
  mlp_layer<256,true,2>(Xh,Xl, w.Whh,          w.Whl,          w.bh,      nullptr, 1, wave,q,r,lane);
  mlp_layer<256,true,2>(Xh,Xl, w.Whh+65536,    w.Whl+65536,    w.bh+256,  nullptr, 1, wave,q,r,lane);
  mlp_layer<256,true,2>(Xh,Xl, w.Whh+131072,   w.Whl+131072,   w.bh+512,  nullptr, 1, wave,q,r,lane);

  // sigma/mu/sig heads (exact h+l reads): 8 lanes per row, cols p*32..p*32+31
  {
    int row = tid>>3, p = tid&7;
    int m = row>>4, rr_ = row&15;
    float s0=0.f, s1=0.f, s2=0.f;
    #pragma unroll
    for (int i=0;i<4;i++){
      int a = XTILE(m,p) + ((i<<4) + rr_)*8;
      f16x8 vh = *(const f16x8*)&Xh[a];
      f16x8 vl = *(const f16x8*)&Xl[a];
      #pragma unroll
      for (int e=0;e<8;e++){
        int k = p*32 + i*8 + e;
        float xv = (float)vh[e] + (float)vl[e];
        s0 = fmaf(xv, w.Ws[k], s0);
        s1 = fmaf(xv, w.Wm[2*k], s1);
        s2 = fmaf(xv, w.Wm[2*k+1], s2);
      }
    }
    s0 += __shfl_xor(s0,1); s0 += __shfl_xor(s0,2); s0 += __shfl_xor(s0,4);
    s1 += __shfl_xor(s1,1); s1 += __shfl_xor(s1,2); s1 += __shfl_xor(s1,4);
    s2 += __shfl_xor(s2,1); s2 += __shfl_xor(s2,2); s2 += __shfl_xor(s2,4);
    if (p==0){
      sh_sig[row] = s0 + w.bs[0];
      sh_mu[row]  = sigmoidf(s1 + w.bm[0]);
      sh_sgm[row] = 2.f*(sigmoidf(s2 + w.bm[1]) + 0.001f);
    }
  }

  // rgb path: lite single-MFMA (only affects rgb_c, which tolerates full f16)
  mlp_layer<256,false,2>(Xh,Xl, w.Wbh, w.Wbl, w.bb, nullptr, 0, wave,q,r,lane);
  mlp_layer128<256,2>(Xh, w.Wdh, w.Wdl, sh_dctr, wave,q,r,lane);

  // rgb head (h-only reads): cols p*16..p*16+15
  {
    int row = tid>>3, p = tid&7;
    int m = row>>4, rr_ = row&15;
    int kt = p>>1, qb = (p&1)*2;
    float s0=0.f,s1=0.f,s2=0.f;
    #pragma unroll
    for (int i=0;i<2;i++){
      int a = XTILE(m,kt) + (((qb+i)<<4) + rr_)*8;
      f16x8 vh = *(const f16x8*)&Xh[a];
      #pragma unroll
      for (int e=0;e<8;e++){
        int k = p*16 + i*8 + e;
        float hv = (float)vh[e];
        s0 = fmaf(hv, w.Wr[3*k  ], s0);
        s1 = fmaf(hv, w.Wr[3*k+1], s1);
        s2 = fmaf(hv, w.Wr[3*k+2], s2);
      }
    }
    s0 += __shfl_xor(s0,1); s0 += __shfl_xor(s0,2); s0 += __shfl_xor(s0,4);
    s1 += __shfl_xor(s1,1); s1 += __shfl_xor(s1,2); s1 += __shfl_xor(s1,4);
    s2 += __shfl_xor(s2,1); s2 += __shfl_xor(s2,2); s2 += __shfl_xor(s2,4);
    if (p==0){
      sh_rgb[row*3  ] = s0 + w.br[0];
      sh_rgb[row*3+1] = s1 + w.br[1];
      sh_rgb[row*3+2] = s2 + w.br[2];
    }
  }
  __syncthreads();

  // ---- volume render + sampling ----
  float alpha = 0.f;
  if (tid < 128){
    float sg = fmaxf(sh_sig[tid], 0.f);
    alpha = 1.f - expf(-sg * (0.03125f*rn));
    float mu = sh_mu[tid], sm = sh_sgm[tid];
    float lt = approx_cdf_f((0.f-mu)/sm);
    sh_lt[tid] = lt;
    sh_pib[tid] = approx_cdf_f((1.f-mu)/sm) - lt;
  }
  float incl = 1.f;
  if (tid < 128){
    incl = 1.f - alpha + 1e-10f;
    #pragma unroll
    for (int off=1; off<64; off<<=1){
      float y = __shfl_up(incl, off);
      if (lane >= off) incl *= y;
    }
    if (lane == 63) red[8 + (tid>>6)] = incl;
  }
  __syncthreads();
  if (tid < 128){
    float basep = (tid >= 64) ? red[8] : 1.f;
    float prev = __shfl_up(incl, 1);
    float excl = (lane == 0) ? 1.f : prev;
    sh_w[tid] = alpha * excl * basep;
  }
  __syncthreads();

  {
    float a0=0.f,a1=0.f,a2=0.f,a3=0.f;
    if (tid < 128){
      float wv = sh_w[tid];
      a0 = wv*sigmoidf(sh_rgb[tid*3+0]);
      a1 = wv*sigmoidf(sh_rgb[tid*3+1]);
      a2 = wv*sigmoidf(sh_rgb[tid*3+2]);
      a3 = wv + 1e-5f;
      #pragma unroll
      for (int off=32; off>0; off>>=1){
        a0 += __shfl_down(a0,off); a1 += __shfl_down(a1,off);
        a2 += __shfl_down(a2,off); a3 += __shfl_down(a3,off);
      }
      if (lane == 0){
        int wv2 = tid>>6;
        red[wv2*4+0]=a0; red[wv2*4+1]=a1; red[wv2*4+2]=a2; red[wv2*4+3]=a3;
      }
    }
    __syncthreads();
    if (tid==0){
      dout[ray*3  ] = red[0]+red[4];
      dout[ray*3+1] = red[1]+red[5];
      dout[ray*3+2] = red[2]+red[6];
      s_wsum = red[3]+red[7];
    }
  }
  __syncthreads();

  float aincl = 0.f;
  if (tid < 128){
    sh_pdf[tid] = (sh_w[tid]+1e-5f)/s_wsum;
    aincl = sh_pdf[tid];
    #pragma unroll
    for (int off=1; off<64; off<<=1){
      float y = __shfl_up(aincl, off);
      if (lane >= off) aincl += y;
    }
    if (lane == 63) red[12 + (tid>>6)] = aincl;
  }
  __syncthreads();
  if (tid < 128){
    float addp = (tid >= 64) ? red[12] : 0.f;
    sh_cdf[tid+1] = aincl + addp;
    if (tid == 0) sh_cdf[0] = 0.f;
  }
  __syncthreads();

  if (tid < 129){
    float u = (float)tid * ((1.f-1e-5f)/128.f);
    int lo=0, hi=129;
    while (lo<hi){ int mid=(lo+hi)>>1; if (sh_cdf[mid] <= u) lo=mid+1; else hi=mid; }
    int idx = lo-1; idx = idx<0?0:(idx>127?127:idx);
    float frac = (u - sh_cdf[idx]) / fmaxf(sh_pdf[idx], 1e-10f);
    frac = fminf(fmaxf(frac,0.f),1.f);
    float p = sh_lt[idx] + frac*sh_pib[idx];
    p = fminf(fmaxf(p, 1e-5f), 1.f-1e-5f);
    float xx = sh_mu[idx] + sh_sgm[idx]*1.4142135623730951f*erfinvf_dev(2.f*p-1.f);
    xx = fminf(fmaxf(xx,0.f),1.f);
    float b0 = 2.f + 0.03125f*(float)idx;
    tfine_out[(size_t)ray*129+tid] = b0 + xx*0.03125f;
  }
}

// ---------- FINE: pure f16 (single MFMA per step); 2 blocks/CU ----------
__global__ __launch_bounds__(1024,8) void k_fine(
    const float* __restrict__ ro, const float* __restrict__ rd, const float* __restrict__ rr,
    Weights w, const float* __restrict__ tfine_in, float* __restrict__ dout)
{
  __shared__ f16 Xh[32768];
  __shared__ float sh_t[132];
  __shared__ float sh_de[32];
  __shared__ float sh_dctr[128];
  __shared__ float sh_sig[128];
  __shared__ float sh_rgb[3*128];
  __shared__ float red[16];
  __shared__ float sh_w[128];

  int ray = blockIdx.x, tid = threadIdx.x;
  int wave = tid>>6, lane = tid&63, q = lane>>4, r = lane&15;

  float rdx = rd[ray*3], rdy = rd[ray*3+1], rdz = rd[ray*3+2];
  float rn = sqrtf(rdx*rdx+rdy*rdy+rdz*rdz);

  if (tid <= 128) sh_t[tid] = tfine_in[(size_t)ray*129 + tid];
  if (tid < 27){
    float v0=rdx/rn, v1=rdy/rn, v2=rdz/rn;
    float vv[3] = {v0,v1,v2};
    float o;
    if (tid < 3) o = vv[tid];
    else if (tid < 15){ int f=(tid-3)/3, j=(tid-3)%3; o = sinf(vv[j]*(float)(1<<f)); }
    else            { int f=(tid-15)/3, j=(tid-15)%3; o = cosf(vv[j]*(float)(1<<f)); }
    sh_de[tid] = o;
  }
  __syncthreads();

  {
    int s = tid >> 3, p = tid & 7;
    float t0 = sh_t[s], t1 = sh_t[s+1];
    float rrv = rr[ray];
    float rdv[3] = {rdx, rdy, rdz};
    float rov[3] = {ro[ray*3], ro[ray*3+1], ro[ray*3+2]};
    float dd = rdx*rdx+rdy*rdy+rdz*rdz;
    float invdd = 1.f/fmaxf(dd, 1e-10f);
    #pragma unroll
    for (int j=0;j<3;j++){
      #pragma unroll
      for (int kk=p*2; kk<p*2+2; kk++){
        float a0, a1;
        enc_vals(t0,t1,rrv,rov,rdv,invdd,j,kk,a0,a1);
        Xh[xaddr(s, kk*3 + j)]      = (f16)a0;
        Xh[xaddr(s, 48 + kk*3 + j)] = (f16)a1;
      }
    }
    #pragma unroll
    for (int i=0;i<4;i++) Xh[xaddr(s, 96 + p*4 + i)] = (f16)0.f;
  }
  __syncthreads();

  if (tid < 128){
    float acc = w.bd[tid];
    #pragma unroll
    for (int k=0;k<27;k++) acc = fmaf(sh_de[k], w.Wdfull[(size_t)(256+k)*128 + tid], acc);
    sh_dctr[tid] = acc;
  }

  mlp_layer<128,false,1>(Xh,nullptr, w.W0h, w.W0l, w.b0, nullptr, 1, wave,q,r,lane);
  mlp_layer<256,false,1>(Xh,nullptr, w.Whh,          w.Whl,          w.bh,      nullptr, 1, wave,q,r,lane);
  mlp_layer<256,false,1>(Xh,nullptr, w.Whh+65536,    w.Whl+65536,    w.bh+256,  nullptr, 1, wave,q,r,lane);
  mlp_layer<256,false,1>(Xh,nullptr, w.Whh+131072,   w.Whl+131072,   w.bh+512,  nullptr, 1, wave,q,r,lane);

  // sigma head (h-only): cols p*32..p*32+31
  {
    int row = tid>>3, p = tid&7;
    int m = row>>4, rr_ = row&15;
    float s0=0.f;
    #pragma unroll
    for (int i=0;i<4;i++){
      int a = XTILE(m,p) + ((i<<4) + rr_)*8;
      f16x8 vh = *(const f16x8*)&Xh[a];
      #pragma unroll
      for (int e=0;e<8;e++) s0 = fmaf((float)vh[e], w.Ws[p*32+i*8+e], s0);
    }
    s0 += __shfl_xor(s0,1); s0 += __shfl_xor(s0,2); s0 += __shfl_xor(s0,4);
    if (p==0) sh_sig[row] = s0 + w.bs[0];
  }

  mlp_layer<256,false,1>(Xh,nullptr, w.Wbh, w.Wbl, w.bb, nullptr, 0, wave,q,r,lane);
  mlp_layer128<256,1>(Xh, w.Wdh, w.Wdl, sh_dctr, wave,q,r,lane);

  // rgb head: cols p*16..p*16+15
  {
    int row = tid>>3, p = tid&7;
    int m = row>>4, rr_ = row&15;
    int kt = p>>1, qb = (p&1)*2;
    float s0=0.f,s1=0.f,s2=0.f;
    #pragma unroll
    for (int i=0;i<2;i++){
      int a = XTILE(m,kt) + (((qb+i)<<4) + rr_)*8;
      f16x8 vh = *(const f16x8*)&Xh[a];
      #pragma unroll
      for (int e=0;e<8;e++){
        int k = p*16 + i*8 + e;
        float hv = (float)vh[e];
        s0 = fmaf(hv, w.Wr[3*k  ], s0);
        s1 = fmaf(hv, w.Wr[3*k+1], s1);
        s2 = fmaf(hv, w.Wr[3*k+2], s2);
      }
    }
    s0 += __shfl_xor(s0,1); s0 += __shfl_xor(s0,2); s0 += __shfl_xor(s0,4);
    s1 += __shfl_xor(s1,1); s1 += __shfl_xor(s1,2); s1 += __shfl_xor(s1,4);
    s2 += __shfl_xor(s2,1); s2 += __shfl_xor(s2,2); s2 += __shfl_xor(s2,4);
    if (p==0){
      sh_rgb[row*3  ] = s0 + w.br[0];
      sh_rgb[row*3+1] = s1 + w.br[1];
      sh_rgb[row*3+2] = s2 + w.br[2];
    }
  }
  __syncthreads();

  float alpha = 0.f;
  if (tid < 128){
    float sg = fmaxf(sh_sig[tid], 0.f);
    alpha = 1.f - expf(-sg*(sh_t[tid+1]-sh_t[tid])*rn);
  }
  float incl = 1.f;
  if (tid < 128){
    incl = 1.f - alpha + 1e-10f;
    #pragma unroll
    for (int off=1; off<64; off<<=1){
      float y = __shfl_up(incl, off);
      if (lane >= off) incl *= y;
    }
    if (lane == 63) red[8 + (tid>>6)] = incl;
  }
  __syncthreads();
  if (tid < 128){
    float basep = (tid >= 64) ? red[8] : 1.f;
    float prev = __shfl_up(incl, 1);
    float excl = (lane == 0) ? 1.f : prev;
    sh_w[tid] = alpha * excl * basep;
  }
  __syncthreads();

  {
    float a0=0.f,a1=0.f,a2=0.f,a3=0.f,a4=0.f;
    if (tid < 128){
      float wv = sh_w[tid];
      a0 = wv*sigmoidf(sh_rgb[tid*3+0]);
      a1 = wv*sigmoidf(sh_rgb[tid*3+1]);
      a2 = wv*sigmoidf(sh_rgb[tid*3+2]);
      a3 = wv*0.5f*(sh_t[tid]+sh_t[tid+1]);
      a4 = wv;
      #pragma unroll
      for (int off=32; off>0; off>>=1){
        a0 += __shfl_down(a0,off); a1 += __shfl_down(a1,off);
        a2 += __shfl_down(a2,off); a3 += __shfl_down(a3,off);
        a4 += __shfl_down(a4,off);
      }
      if (lane == 0){
        int wv2 = tid>>6;
        red[wv2*5+0]=a0; red[wv2*5+1]=a1; red[wv2*5+2]=a2; red[wv2*5+3]=a3; red[wv2*5+4]=a4;
      }
    }
    __syncthreads();
    if (tid==0){
      dout[NRAYS*3 + ray*3  ] = red[0]+red[5];
      dout[NRAYS*3 + ray*3+1] = red[1]+red[6];
      dout[NRAYS*3 + ray*3+2] = red[2]+red[7];
      dout[NRAYS*6 + ray] = red[3]+red[8];
      dout[NRAYS*7 + ray] = red[4]+red[9];
    }
  }
}

extern "C" void kernel_launch(void* const* d_in, const int* in_sizes, int n_in,
                              void* d_out, int out_size, void* d_ws, size_t ws_size,
                              hipStream_t stream) {
  const float* ro  = (const float*)d_in[0];
  const float* rd  = (const float*)d_in[1];
  const float* rr  = (const float*)d_in[2];
  const float* cW0 = (const float*)d_in[3];  const float* cb0 = (const float*)d_in[4];
  const float* cWh = (const float*)d_in[5];  const float* cbh = (const float*)d_in[6];
  const float* cWs = (const float*)d_in[7];  const float* cbs = (const float*)d_in[8];
  const float* cWb = (const float*)d_in[9];  const float* cbb = (const float*)d_in[10];
  const float* cWd = (const float*)d_in[11]; const float* cbd = (const float*)d_in[12];
  const float* cWr = (const float*)d_in[13]; const float* cbr = (const float*)d_in[14];
  int iWm = 27, ibm = 28, ifb = 15;
  if (n_in > 15 && in_sizes[15] == 512){ iWm = 15; ibm = 16; ifb = 17; }
  const float* fW0 = (const float*)d_in[ifb+0];  const float* fb0 = (const float*)d_in[ifb+1];
  const float* fWh = (const float*)d_in[ifb+2];  const float* fbh = (const float*)d_in[ifb+3];
  const float* fWs = (const float*)d_in[ifb+4];  const float* fbs = (const float*)d_in[ifb+5];
  const float* fWb = (const float*)d_in[ifb+6];  const float* fbb = (const float*)d_in[ifb+7];
  const float* fWd = (const float*)d_in[ifb+8];  const float* fbd = (const float*)d_in[ifb+9];
  const float* fWr = (const float*)d_in[ifb+10]; const float* fbr = (const float*)d_in[ifb+11];
  const float* cWm = (const float*)d_in[iWm];    const float* cbm = (const float*)d_in[ibm];

  char* base = (char*)d_ws;
  size_t off = 0;
  auto alloc = [&](size_t bytes)->void*{ off = (off+63) & ~(size_t)63; void* p = base+off; off += bytes; return p; };

  float* tfine = (float*)alloc((size_t)NRAYS*129*4);
  f16 *cW0h=(f16*)alloc((size_t)256*128*2), *cW0l=(f16*)alloc((size_t)256*128*2);
  f16 *cWhh=(f16*)alloc((size_t)3*256*256*2), *cWhl=(f16*)alloc((size_t)3*256*256*2);
  f16 *cWbh=(f16*)alloc((size_t)256*256*2), *cWbl=(f16*)alloc((size_t)256*256*2);
  f16 *cWdh=(f16*)alloc((size_t)128*256*2), *cWdl=(f16*)alloc((size_t)128*256*2);
  f16 *fW0h=(f16*)alloc((size_t)256*128*2), *fW0l=(f16*)alloc((size_t)256*128*2);
  f16 *fWhh=(f16*)alloc((size_t)3*256*256*2), *fWhl=(f16*)alloc((size_t)3*256*256*2);
  f16 *fWbh=(f16*)alloc((size_t)256*256*2), *fWbl=(f16*)alloc((size_t)256*256*2);
  f16 *fWdh=(f16*)alloc((size_t)128*256*2), *fWdl=(f16*)alloc((size_t)128*256*2);

  k_cvtT<<<(256*128+255)/256,256,0,stream>>>(cW0, cW0h, cW0l, 96, 256, 128);
  for (int i=0;i<3;i++)
    k_cvtT<<<(256*256+255)/256,256,0,stream>>>(cWh+(size_t)i*65536, cWhh+(size_t)i*65536, cWhl+(size_t)i*65536, 256, 256, 256);
  k_cvtT<<<(256*256+255)/256,256,0,stream>>>(cWb, cWbh, cWbl, 256, 256, 256);
  k_cvtT<<<(128*256+255)/256,256,0,stream>>>(cWd, cWdh, cWdl, 256, 128, 256);
  k_cvtT<<<(256*128+255)/256,256,0,stream>>>(fW0, fW0h, fW0l, 96, 256, 128);
  for (int i=0;i<3;i++)
    k_cvtT<<<(256*256+255)/256,256,0,stream>>>(fWh+(size_t)i*65536, fWhh+(size_t)i*65536, fWhl+(size_t)i*65536, 256, 256, 256);
  k_cvtT<<<(256*256+255)/256,256,0,stream>>>(fWb, fWbh, fWbl, 256, 256, 256);
  k_cvtT<<<(128*256+255)/256,256,0,stream>>>(fWd, fWdh, fWdl, 256, 128, 256);

  Weights wc = { cW0h,cW0l,cb0, cWhh,cWhl,cbh, cWs,cbs,cWm,cbm,
                 cWbh,cWbl,cbb, cWdh,cWdl,cWd,cbd, cWr,cbr };
  Weights wf = { fW0h,fW0l,fb0, fWhh,fWhl,fbh, fWs,fbs,nullptr,nullptr,
                 fWbh,fWbl,fbb, fWdh,fWdl,fWd,fbd, fWr,fbr };

  k_coarse<<<NRAYS,1024,0,stream>>>(ro, rd, rr, wc, tfine, (float*)d_out);
  k_fine  <<<NRAYS,1024,0,stream>>>(ro, rd, rr, wf, tfine, (float*)d_out);
}

// Round 16
// 893.160 us; speedup vs baseline: 1.0426x; 1.0426x over previous
//
#include <hip/hip_runtime.h>

#define NRAYS 2048
// X stored in MFMA-fragment order: tile (m=row/16, kt=col/32) at ((m*8+kt)*512),
// within tile: lane-chunk (q=col%32/8)*16 + (r=row%16), 8 f16 per chunk (col%8).
#define XTILE(m,kt) ((((m)<<3)+(kt))<<9)
__device__ __forceinline__ int xaddr(int row, int col){
  return XTILE(row>>4, col>>5) + ((((col&31)>>3)<<4) + (row&15))*8 + (col&7);
}

typedef _Float16 f16;
typedef __attribute__((ext_vector_type(4))) _Float16 f16x4;
typedef __attribute__((ext_vector_type(8))) _Float16 f16x8;
typedef __attribute__((ext_vector_type(4))) float f32x4;

__device__ __forceinline__ float sigmoidf(float x){ return 1.f/(1.f+expf(-x)); }

__device__ __forceinline__ float approx_cdf_f(float x){
  return 0.5f*(1.f + tanhf(0.7978845608028654f*(x + 0.044715f*x*x*x)));
}

// Giles (2010) single-precision erfinv, max rel err ~1e-6
__device__ __forceinline__ float erfinvf_dev(float x){
  float w = -logf((1.0f-x)*(1.0f+x));
  float p;
  if (w < 5.0f){
    w -= 2.5f;
    p = 2.81022636e-08f;
    p = fmaf(p,w, 3.43273939e-07f);
    p = fmaf(p,w,-3.5233877e-06f);
    p = fmaf(p,w,-4.39150654e-06f);
    p = fmaf(p,w, 0.00021858087f);
    p = fmaf(p,w,-0.00125372503f);
    p = fmaf(p,w,-0.00417768164f);
    p = fmaf(p,w, 0.246640727f);
    p = fmaf(p,w, 1.50140941f);
  } else {
    w = sqrtf(w) - 3.0f;
    p = -0.000200214257f;
    p = fmaf(p,w, 0.000100950558f);
    p = fmaf(p,w, 0.00134934322f);
    p = fmaf(p,w,-0.00367342844f);
    p = fmaf(p,w, 0.00573950773f);
    p = fmaf(p,w,-0.0076224613f);
    p = fmaf(p,w, 0.00943887047f);
    p = fmaf(p,w, 1.00167406f);
    p = fmaf(p,w, 2.83297682f);
  }
  return p*x;
}

// ---------- fused weight convert: 12 jobs in one launch ----------
struct CvtJob { const float* src; f16* dh; f16* dl; int Ksrc, N, Kdst, blkBase; };
struct CvtJobs { CvtJob j[12]; };

__global__ void k_cvt_all(CvtJobs jobs){
  int b = blockIdx.x;
  // find job: linear scan (12 entries)
  int ji = 0;
  #pragma unroll
  for (int i=1;i<12;i++) if (b >= jobs.j[i].blkBase) ji = i;
  const CvtJob& J = jobs.j[ji];
  int g = (b - J.blkBase)*256 + threadIdx.x;
  if (g >= J.N*J.Kdst) return;
  int n = g / J.Kdst, k = g - n*J.Kdst;
  float v = (k < J.Ksrc) ? J.src[(size_t)k*J.N + n] : 0.f;
  f16 h = (f16)v;
  J.dh[g] = h;
  J.dl[g] = (f16)(v - (float)h);
}

struct Weights {
  const f16 *W0h,*W0l; const float *b0;
  const f16 *Whh,*Whl; const float *bh;
  const float *Ws,*bs,*Wm,*bm;      // Wm,bm only used by coarse
  const f16 *Wbh,*Wbl; const float *bb;
  const f16 *Wdh,*Wdl; const float *Wdfull,*bd;
  const float *Wr,*br;
};

// One layer: X(128 x K, fragment-order LDS) @ BT^T (N=256 x K, L2) -> X.
// 16 waves; wave covers 16 output cols; 8 m-tiles -> acc[8]. PF=1 B-prefetch.
// TRANSPOSED MFMA: acc = mfma(Bfrag, Afrag) = C^T; lane (q,r) holds row m*16+r,
// cols nbase+q*4..+3 -> single b64 write into fragment layout.
// SPLIT: acc = Bh*Ah + Bl*Ah + Bh*Al (fp32-equivalent), writes h+l.
// !SPLIT: acc = Bh*Ah (pure f16), reads/writes h only.
template<int K, bool SPLIT>
__device__ __forceinline__ void mlp_layer(
    f16* __restrict__ Xh, f16* __restrict__ Xl,
    const f16* __restrict__ Bh, const f16* __restrict__ Bl,
    const float* __restrict__ bias, const float* dctr, int relu,
    int wave, int q, int r, int lane)
{
  const int nbase = wave * 16;
  f32x4 acc[8];
  #pragma unroll
  for (int m=0;m<8;m++) acc[m] = (f32x4){0.f,0.f,0.f,0.f};
  {
    const f16* bhp = Bh + (size_t)(nbase + r)*K + q*8;
    const f16* blp = Bl + (size_t)(nbase + r)*K + q*8;
    f16x8 bh = *(const f16x8*)bhp;
    f16x8 bl;
    if (SPLIT) bl = *(const f16x8*)blp;
    #pragma unroll
    for (int k0=0;k0<K;k0+=32){
      const int kt = k0 >> 5;
      f16x8 bh_n, bl_n;
      if (k0+32 < K){
        bh_n = *(const f16x8*)(bhp + k0 + 32);
        if (SPLIT) bl_n = *(const f16x8*)(blp + k0 + 32);
      }
      #pragma unroll
      for (int m=0;m<8;m++){
        int ao = XTILE(m,kt) + (lane<<3);
        f16x8 ah = *(const f16x8*)&Xh[ao];
        acc[m] = __builtin_amdgcn_mfma_f32_16x16x32_f16(bh, ah, acc[m], 0,0,0);
        if (SPLIT){
          f16x8 al = *(const f16x8*)&Xl[ao];
          acc[m] = __builtin_amdgcn_mfma_f32_16x16x32_f16(bl, ah, acc[m], 0,0,0);
          acc[m] = __builtin_amdgcn_mfma_f32_16x16x32_f16(bh, al, acc[m], 0,0,0);
        }
      }
      bh = bh_n;
      if (SPLIT) bl = bl_n;
    }
  }
  __syncthreads();   // all waves done reading X
  {
    const int c0 = nbase + q*4;
    const int ktp = c0 >> 5, qp = (c0 & 31) >> 3, j0 = c0 & 7;
    float ba0=0.f,ba1=0.f,ba2=0.f,ba3=0.f;
    if (bias){ ba0=bias[c0]; ba1=bias[c0+1]; ba2=bias[c0+2]; ba3=bias[c0+3]; }
    if (dctr){ ba0+=dctr[c0]; ba1+=dctr[c0+1]; ba2+=dctr[c0+2]; ba3+=dctr[c0+3]; }
    #pragma unroll
    for (int m=0;m<8;m++){
      int ao = XTILE(m,ktp) + ((qp<<4) + r)*8 + j0;
      float v0 = acc[m][0] + ba0, v1 = acc[m][1] + ba1;
      float v2 = acc[m][2] + ba2, v3 = acc[m][3] + ba3;
      if (relu){ v0=fmaxf(v0,0.f); v1=fmaxf(v1,0.f); v2=fmaxf(v2,0.f); v3=fmaxf(v3,0.f); }
      f16 h0=(f16)v0, h1=(f16)v1, h2=(f16)v2, h3=(f16)v3;
      f16x4 hv = {h0,h1,h2,h3};
      *(f16x4*)&Xh[ao] = hv;
      if (SPLIT){
        f16x4 lv = {(f16)(v0-(float)h0),(f16)(v1-(float)h1),(f16)(v2-(float)h2),(f16)(v3-(float)h3)};
        *(f16x4*)&Xl[ao] = lv;
      }
    }
  }
  __syncthreads();
}

// Wd layer variant: N=128 output cols, ALL 16 waves active:
// cg = wave&7 -> 16 cols; mh = wave>>3 -> m-tiles mh*4..mh*4+3 (acc[4]).  PF=1.
template<int K>
__device__ __forceinline__ void mlp_layer128(
    f16* __restrict__ Xh,
    const f16* __restrict__ Bh,
    const float* dctr, int wave, int q, int r, int lane)
{
  const int nbase = (wave & 7) * 16;
  const int mbase = (wave >> 3) * 4;
  f32x4 acc[4];
  #pragma unroll
  for (int m=0;m<4;m++) acc[m] = (f32x4){0.f,0.f,0.f,0.f};
  {
    const f16* bhp = Bh + (size_t)(nbase + r)*K + q*8;
    f16x8 bh = *(const f16x8*)bhp;
    #pragma unroll
    for (int k0=0;k0<K;k0+=32){
      const int kt = k0 >> 5;
      f16x8 bh_n;
      if (k0+32 < K) bh_n = *(const f16x8*)(bhp + k0 + 32);
      #pragma unroll
      for (int m=0;m<4;m++){
        int ao = XTILE(mbase+m,kt) + (lane<<3);
        f16x8 ah = *(const f16x8*)&Xh[ao];
        acc[m] = __builtin_amdgcn_mfma_f32_16x16x32_f16(bh, ah, acc[m], 0,0,0);
      }
      bh = bh_n;
    }
  }
  __syncthreads();
  {
    const int c0 = nbase + q*4;
    const int ktp = c0 >> 5, qp = (c0 & 31) >> 3, j0 = c0 & 7;
    float ba0=dctr[c0], ba1=dctr[c0+1], ba2=dctr[c0+2], ba3=dctr[c0+3];
    #pragma unroll
    for (int m=0;m<4;m++){
      int ao = XTILE(mbase+m,ktp) + ((qp<<4) + r)*8 + j0;
      float v0 = fmaxf(acc[m][0] + ba0, 0.f), v1 = fmaxf(acc[m][1] + ba1, 0.f);
      float v2 = fmaxf(acc[m][2] + ba2, 0.f), v3 = fmaxf(acc[m][3] + ba3, 0.f);
      f16x4 hv = {(f16)v0,(f16)v1,(f16)v2,(f16)v3};
      *(f16x4*)&Xh[ao] = hv;
    }
  }
  __syncthreads();
}

// shared enc math
__device__ __forceinline__ void enc_vals(
    float t0, float t1, float rrv,
    const float* rov, const float* rdv, float invdd,
    int j, int kk, float& a0, float& a1)
{
  float c = 0.5f*(t0+t1), d = 0.5f*(t1-t0);
  float c2 = c*c, d2 = d*d;
  float denom = 3.f*c2 + d2;
  float t_mean = c + 2.f*c*d2/denom;
  float d4 = d2*d2;
  float t_var = d2*(1.f/3.f) - (4.f/15.f)*(d4*(12.f*c2 - d2))/(denom*denom);
  float r_var = rrv*rrv*(c2*0.25f + (5.f/12.f)*d2 - (4.f/15.f)*d4/denom);
  float mean = rov[j] + rdv[j]*t_mean;
  float doj = rdv[j]*rdv[j];
  float cov = t_var*doj + r_var*(1.f - doj*invdd);
  float sc = (float)(1<<kk);
  float att = expf(-0.5f*cov*sc*sc);
  float sv, cv;
  sincosf(mean*sc, &sv, &cv);
  a0 = sv*att; a1 = cv*att;
}

// ---------- COARSE: enc + exact trunk + heads + lite rgb-path + render + sampling ----------
__global__ __launch_bounds__(1024,4) void k_coarse(
    const float* __restrict__ ro, const float* __restrict__ rd, const float* __restrict__ rr,
    Weights w, float* __restrict__ tfine_out, float* __restrict__ dout)
{
  __shared__ f16 Xh[32768];
  __shared__ f16 Xl[32768];
  __shared__ float sh_de[32];
  __shared__ float sh_dctr[128];
  __shared__ float sh_sig[128], sh_mu[128], sh_sgm[128];
  __shared__ float sh_rgb[3*128];
  __shared__ float red[16];
  __shared__ float sh_w[128], sh_pdf[128], sh_cdf[132], sh_lt[128], sh_pib[128];
  __shared__ float s_wsum;

  int ray = blockIdx.x, tid = threadIdx.x;
  int wave = tid>>6, lane = tid&63, q = lane>>4, r = lane&15;

  float rdx = rd[ray*3], rdy = rd[ray*3+1], rdz = rd[ray*3+2];
  float rn = sqrtf(rdx*rdx+rdy*rdy+rdz*rdz);

  if (tid < 27){
    float v0=rdx/rn, v1=rdy/rn, v2=rdz/rn;
    float vv[3] = {v0,v1,v2};
    float o;
    if (tid < 3) o = vv[tid];
    else if (tid < 15){ int f=(tid-3)/3, j=(tid-3)%3; o = sinf(vv[j]*(float)(1<<f)); }
    else            { int f=(tid-15)/3, j=(tid-15)%3; o = cosf(vv[j]*(float)(1<<f)); }
    sh_de[tid] = o;
  }

  // enc (h+l): sample s = tid>>3, part p = tid&7 handles freqs p*2..p*2+1
  {
    int s = tid >> 3, p = tid & 7;
    float t0 = 2.f + 0.03125f*(float)s, t1 = t0 + 0.03125f;
    float rrv = rr[ray];
    float rdv[3] = {rdx, rdy, rdz};
    float rov[3] = {ro[ray*3], ro[ray*3+1], ro[ray*3+2]};
    float dd = rdx*rdx+rdy*rdy+rdz*rdz;
    float invdd = 1.f/fmaxf(dd, 1e-10f);
    #pragma unroll
    for (int j=0;j<3;j++){
      #pragma unroll
      for (int kk=p*2; kk<p*2+2; kk++){
        float a0, a1;
        enc_vals(t0,t1,rrv,rov,rdv,invdd,j,kk,a0,a1);
        f16 h0=(f16)a0, h1=(f16)a1;
        int i0 = xaddr(s, kk*3 + j), i1 = xaddr(s, 48 + kk*3 + j);
        Xh[i0]=h0; Xl[i0]=(f16)(a0-(float)h0);
        Xh[i1]=h1; Xl[i1]=(f16)(a1-(float)h1);
      }
    }
    #pragma unroll
    for (int i=0;i<4;i++){
      int a = xaddr(s, 96 + p*4 + i);
      Xh[a]=(f16)0.f; Xl[a]=(f16)0.f;
    }
  }
  __syncthreads();

  if (tid < 128){
    float acc = w.bd[tid];
    #pragma unroll
    for (int k=0;k<27;k++) acc = fmaf(sh_de[k], w.Wdfull[(size_t)(256+k)*128 + tid], acc);
    sh_dctr[tid] = acc;
  }

  // ---- exact trunk (feeds the chaotic sampler) ----
  mlp_layer<128,true>(Xh,Xl, w.W0h, w.W0l, w.b0, nullptr, 1, wave,q,r,lane);
  mlp_layer<256,true>(Xh,Xl, w.Whh,          w.Whl,          w.bh,      nullptr, 1, wave,q,r,lane);
  mlp_layer<256,true>(Xh,Xl, w.Whh+65536,    w.Whl+65536,    w.bh+256,  nullptr, 1, wave,q,r,lane);
  mlp_layer<256,true>(Xh,Xl, w.Whh+131072,   w.Whl+131072,   w.bh+512,  nullptr, 1, wave,q,r,lane);

  // sigma/mu/sig heads (exact h+l reads): 8 lanes per row, cols p*32..p*32+31
  {
    int row = tid>>3, p = tid&7;
    int m = row>>4, rr_ = row&15;
    float s0=0.f, s1=0.f, s2=0.f;
    #pragma unroll
    for (int i=0;i<4;i++){
      int a = XTILE(m,p) + ((i<<4) + rr_)*8;
      f16x8 vh = *(const f16x8*)&Xh[a];
      f16x8 vl = *(const f16x8*)&Xl[a];
      #pragma unroll
      for (int e=0;e<8;e++){
        int k = p*32 + i*8 + e;
        float xv = (float)vh[e] + (float)vl[e];
        s0 = fmaf(xv, w.Ws[k], s0);
        s1 = fmaf(xv, w.Wm[2*k], s1);
        s2 = fmaf(xv, w.Wm[2*k+1], s2);
      }
    }
    s0 += __shfl_xor(s0,1); s0 += __shfl_xor(s0,2); s0 += __shfl_xor(s0,4);
    s1 += __shfl_xor(s1,1); s1 += __shfl_xor(s1,2); s1 += __shfl_xor(s1,4);
    s2 += __shfl_xor(s2,1); s2 += __shfl_xor(s2,2); s2 += __shfl_xor(s2,4);
    if (p==0){
      sh_sig[row] = s0 + w.bs[0];
      sh_mu[row]  = sigmoidf(s1 + w.bm[0]);
      sh_sgm[row] = 2.f*(sigmoidf(s2 + w.bm[1]) + 0.001f);
    }
  }

  // rgb path: lite single-MFMA (only affects rgb_c, which tolerates full f16)
  mlp_layer<256,false>(Xh,Xl, w.Wbh, w.Wbl, w.bb, nullptr, 0, wave,q,r,lane);
  mlp_layer128<256>(Xh, w.Wdh, sh_dctr, wave,q,r,lane);

  // rgb head (h-only reads): cols p*16..p*16+15
  {
    int row = tid>>3, p = tid&7;
    int m = row>>4, rr_ = row&15;
    int kt = p>>1, qb = (p&1)*2;
    float s0=0.f,s1=0.f,s2=0.f;
    #pragma unroll
    for (int i=0;i<2;i++){
      int a = XTILE(m,kt) + (((qb+i)<<4) + rr_)*8;
      f16x8 vh = *(const f16x8*)&Xh[a];
      #pragma unroll
      for (int e=0;e<8;e++){
        int k = p*16 + i*8 + e;
        float hv = (float)vh[e];
        s0 = fmaf(hv, w.Wr[3*k  ], s0);
        s1 = fmaf(hv, w.Wr[3*k+1], s1);
        s2 = fmaf(hv, w.Wr[3*k+2], s2);
      }
    }
    s0 += __shfl_xor(s0,1); s0 += __shfl_xor(s0,2); s0 += __shfl_xor(s0,4);
    s1 += __shfl_xor(s1,1); s1 += __shfl_xor(s1,2); s1 += __shfl_xor(s1,4);
    s2 += __shfl_xor(s2,1); s2 += __shfl_xor(s2,2); s2 += __shfl_xor(s2,4);
    if (p==0){
      sh_rgb[row*3  ] = s0 + w.br[0];
      sh_rgb[row*3+1] = s1 + w.br[1];
      sh_rgb[row*3+2] = s2 + w.br[2];
    }
  }
  __syncthreads();

  // ---- volume render + sampling ----
  float alpha = 0.f;
  if (tid < 128){
    float sg = fmaxf(sh_sig[tid], 0.f);
    alpha = 1.f - expf(-sg * (0.03125f*rn));
    float mu = sh_mu[tid], sm = sh_sgm[tid];
    float lt = approx_cdf_f((0.f-mu)/sm);
    sh_lt[tid] = lt;
    sh_pib[tid] = approx_cdf_f((1.f-mu)/sm) - lt;
  }
  float incl = 1.f;
  if (tid < 128){
    incl = 1.f - alpha + 1e-10f;
    #pragma unroll
    for (int off=1; off<64; off<<=1){
      float y = __shfl_up(incl, off);
      if (lane >= off) incl *= y;
    }
    if (lane == 63) red[8 + (tid>>6)] = incl;
  }
  __syncthreads();
  if (tid < 128){
    float basep = (tid >= 64) ? red[8] : 1.f;
    float prev = __shfl_up(incl, 1);
    float excl = (lane == 0) ? 1.f : prev;
    sh_w[tid] = alpha * excl * basep;
  }
  __syncthreads();

  {
    float a0=0.f,a1=0.f,a2=0.f,a3=0.f;
    if (tid < 128){
      float wv = sh_w[tid];
      a0 = wv*sigmoidf(sh_rgb[tid*3+0]);
      a1 = wv*sigmoidf(sh_rgb[tid*3+1]);
      a2 = wv*sigmoidf(sh_rgb[tid*3+2]);
      a3 = wv + 1e-5f;
      #pragma unroll
      for (int off=32; off>0; off>>=1){
        a0 += __shfl_down(a0,off); a1 += __shfl_down(a1,off);
        a2 += __shfl_down(a2,off); a3 += __shfl_down(a3,off);
      }
      if (lane == 0){
        int wv2 = tid>>6;
        red[wv2*4+0]=a0; red[wv2*4+1]=a1; red[wv2*4+2]=a2; red[wv2*4+3]=a3;
      }
    }
    __syncthreads();
    if (tid==0){
      dout[ray*3  ] = red[0]+red[4];
      dout[ray*3+1] = red[1]+red[5];
      dout[ray*3+2] = red[2]+red[6];
      s_wsum = red[3]+red[7];
    }
  }
  __syncthreads();

  float aincl = 0.f;
  if (tid < 128){
    sh_pdf[tid] = (sh_w[tid]+1e-5f)/s_wsum;
    aincl = sh_pdf[tid];
    #pragma unroll
    for (int off=1; off<64; off<<=1){
      float y = __shfl_up(aincl, off);
      if (lane >= off) aincl += y;
    }
    if (lane == 63) red[12 + (tid>>6)] = aincl;
  }
  __syncthreads();
  if (tid < 128){
    float addp = (tid >= 64) ? red[12] : 0.f;
    sh_cdf[tid+1] = aincl + addp;
    if (tid == 0) sh_cdf[0] = 0.f;
  }
  __syncthreads();

  if (tid < 129){
    float u = (float)tid * ((1.f-1e-5f)/128.f);
    int lo=0, hi=129;
    while (lo<hi){ int mid=(lo+hi)>>1; if (sh_cdf[mid] <= u) lo=mid+1; else hi=mid; }
    int idx = lo-1; idx = idx<0?0:(idx>127?127:idx);
    float frac = (u - sh_cdf[idx]) / fmaxf(sh_pdf[idx], 1e-10f);
    frac = fminf(fmaxf(frac,0.f),1.f);
    float p = sh_lt[idx] + frac*sh_pib[idx];
    p = fminf(fmaxf(p, 1e-5f), 1.f-1e-5f);
    float xx = sh_mu[idx] + sh_sgm[idx]*1.4142135623730951f*erfinvf_dev(2.f*p-1.f);
    xx = fminf(fmaxf(xx,0.f),1.f);
    float b0 = 2.f + 0.03125f*(float)idx;
    tfine_out[(size_t)ray*129+tid] = b0 + xx*0.03125f;
  }
}

// ---------- FINE: pure f16 (single MFMA per step); 2 blocks/CU ----------
__global__ __launch_bounds__(1024,8) void k_fine(
    const float* __restrict__ ro, const float* __restrict__ rd, const float* __restrict__ rr,
    Weights w, const float* __restrict__ tfine_in, float* __restrict__ dout)
{
  __shared__ f16 Xh[32768];
  __shared__ float sh_t[132];
  __shared__ float sh_de[32];
  __shared__ float sh_dctr[128];
  __shared__ float sh_sig[128];
  __shared__ float sh_rgb[3*128];
  __shared__ float red[16];
  __shared__ float sh_w[128];

  int ray = blockIdx.x, tid = threadIdx.x;
  int wave = tid>>6, lane = tid&63, q = lane>>4, r = lane&15;

  float rdx = rd[ray*3], rdy = rd[ray*3+1], rdz = rd[ray*3+2];
  float rn = sqrtf(rdx*rdx+rdy*rdy+rdz*rdz);

  if (tid <= 128) sh_t[tid] = tfine_in[(size_t)ray*129 + tid];
  if (tid < 27){
    float v0=rdx/rn, v1=rdy/rn, v2=rdz/rn;
    float vv[3] = {v0,v1,v2};
    float o;
    if (tid < 3) o = vv[tid];
    else if (tid < 15){ int f=(tid-3)/3, j=(tid-3)%3; o = sinf(vv[j]*(float)(1<<f)); }
    else            { int f=(tid-15)/3, j=(tid-15)%3; o = cosf(vv[j]*(float)(1<<f)); }
    sh_de[tid] = o;
  }
  __syncthreads();

  {
    int s = tid >> 3, p = tid & 7;
    float t0 = sh_t[s], t1 = sh_t[s+1];
    float rrv = rr[ray];
    float rdv[3] = {rdx, rdy, rdz};
    float rov[3] = {ro[ray*3], ro[ray*3+1], ro[ray*3+2]};
    float dd = rdx*rdx+rdy*rdy+rdz*rdz;
    float invdd = 1.f/fmaxf(dd, 1e-10f);
    #pragma unroll
    for (int j=0;j<3;j++){
      #pragma unroll
      for (int kk=p*2; kk<p*2+2; kk++){
        float a0, a1;
        enc_vals(t0,t1,rrv,rov,rdv,invdd,j,kk,a0,a1);
        Xh[xaddr(s, kk*3 + j)]      = (f16)a0;
        Xh[xaddr(s, 48 + kk*3 + j)] = (f16)a1;
      }
    }
    #pragma unroll
    for (int i=0;i<4;i++) Xh[xaddr(s, 96 + p*4 + i)] = (f16)0.f;
  }
  __syncthreads();

  if (tid < 128){
    float acc = w.bd[tid];
    #pragma unroll
    for (int k=0;k<27;k++) acc = fmaf(sh_de[k], w.Wdfull[(size_t)(256+k)*128 + tid], acc);
    sh_dctr[tid] = acc;
  }

  mlp_layer<128,false>(Xh,nullptr, w.W0h, w.W0l, w.b0, nullptr, 1, wave,q,r,lane);
  mlp_layer<256,false>(Xh,nullptr, w.Whh,          w.Whl,          w.bh,      nullptr, 1, wave,q,r,lane);
  mlp_layer<256,false>(Xh,nullptr, w.Whh+65536,    w.Whl+65536,    w.bh+256,  nullptr, 1, wave,q,r,lane);
  mlp_layer<256,false>(Xh,nullptr, w.Whh+131072,   w.Whl+131072,   w.bh+512,  nullptr, 1, wave,q,r,lane);

  // sigma head (h-only): cols p*32..p*32+31
  {
    int row = tid>>3, p = tid&7;
    int m = row>>4, rr_ = row&15;
    float s0=0.f;
    #pragma unroll
    for (int i=0;i<4;i++){
      int a = XTILE(m,p) + ((i<<4) + rr_)*8;
      f16x8 vh = *(const f16x8*)&Xh[a];
      #pragma unroll
      for (int e=0;e<8;e++) s0 = fmaf((float)vh[e], w.Ws[p*32+i*8+e], s0);
    }
    s0 += __shfl_xor(s0,1); s0 += __shfl_xor(s0,2); s0 += __shfl_xor(s0,4);
    if (p==0) sh_sig[row] = s0 + w.bs[0];
  }

  mlp_layer<256,false>(Xh,nullptr, w.Wbh, w.Wbl, w.bb, nullptr, 0, wave,q,r,lane);
  mlp_layer128<256>(Xh, w.Wdh, sh_dctr, wave,q,r,lane);

  // rgb head: cols p*16..p*16+15
  {
    int row = tid>>3, p = tid&7;
    int m = row>>4, rr_ = row&15;
    int kt = p>>1, qb = (p&1)*2;
    float s0=0.f,s1=0.f,s2=0.f;
    #pragma unroll
    for (int i=0;i<2;i++){
      int a = XTILE(m,kt) + (((qb+i)<<4) + rr_)*8;
      f16x8 vh = *(const f16x8*)&Xh[a];
      #pragma unroll
      for (int e=0;e<8;e++){
        int k = p*16 + i*8 + e;
        float hv = (float)vh[e];
        s0 = fmaf(hv, w.Wr[3*k  ], s0);
        s1 = fmaf(hv, w.Wr[3*k+1], s1);
        s2 = fmaf(hv, w.Wr[3*k+2], s2);
      }
    }
    s0 += __shfl_xor(s0,1); s0 += __shfl_xor(s0,2); s0 += __shfl_xor(s0,4);
    s1 += __shfl_xor(s1,1); s1 += __shfl_xor(s1,2); s1 += __shfl_xor(s1,4);
    s2 += __shfl_xor(s2,1); s2 += __shfl_xor(s2,2); s2 += __shfl_xor(s2,4);
    if (p==0){
      sh_rgb[row*3  ] = s0 + w.br[0];
      sh_rgb[row*3+1] = s1 + w.br[1];
      sh_rgb[row*3+2] = s2 + w.br[2];
    }
  }
  __syncthreads();

  float alpha = 0.f;
  if (tid < 128){
    float sg = fmaxf(sh_sig[tid], 0.f);
    alpha = 1.f - expf(-sg*(sh_t[tid+1]-sh_t[tid])*rn);
  }
  float incl = 1.f;
  if (tid < 128){
    incl = 1.f - alpha + 1e-10f;
    #pragma unroll
    for (int off=1; off<64; off<<=1){
      float y = __shfl_up(incl, off);
      if (lane >= off) incl *= y;
    }
    if (lane == 63) red[8 + (tid>>6)] = incl;
  }
  __syncthreads();
  if (tid < 128){
    float basep = (tid >= 64) ? red[8] : 1.f;
    float prev = __shfl_up(incl, 1);
    float excl = (lane == 0) ? 1.f : prev;
    sh_w[tid] = alpha * excl * basep;
  }
  __syncthreads();

  {
    float a0=0.f,a1=0.f,a2=0.f,a3=0.f,a4=0.f;
    if (tid < 128){
      float wv = sh_w[tid];
      a0 = wv*sigmoidf(sh_rgb[tid*3+0]);
      a1 = wv*sigmoidf(sh_rgb[tid*3+1]);
      a2 = wv*sigmoidf(sh_rgb[tid*3+2]);
      a3 = wv*0.5f*(sh_t[tid]+sh_t[tid+1]);
      a4 = wv;
      #pragma unroll
      for (int off=32; off>0; off>>=1){
        a0 += __shfl_down(a0,off); a1 += __shfl_down(a1,off);
        a2 += __shfl_down(a2,off); a3 += __shfl_down(a3,off);
        a4 += __shfl_down(a4,off);
      }
      if (lane == 0){
        int wv2 = tid>>6;
        red[wv2*5+0]=a0; red[wv2*5+1]=a1; red[wv2*5+2]=a2; red[wv2*5+3]=a3; red[wv2*5+4]=a4;
      }
    }
    __syncthreads();
    if (tid==0){
      dout[NRAYS*3 + ray*3  ] = red[0]+red[5];
      dout[NRAYS*3 + ray*3+1] = red[1]+red[6];
      dout[NRAYS*3 + ray*3+2] = red[2]+red[7];
      dout[NRAYS*6 + ray] = red[3]+red[8];
      dout[NRAYS*7 + ray] = red[4]+red[9];
    }
  }
}

extern "C" void kernel_launch(void* const* d_in, const int* in_sizes, int n_in,
                              void* d_out, int out_size, void* d_ws, size_t ws_size,
                              hipStream_t stream) {
  const float* ro  = (const float*)d_in[0];
  const float* rd  = (const float*)d_in[1];
  const float* rr  = (const float*)d_in[2];
  const float* cW0 = (const float*)d_in[3];  const float* cb0 = (const float*)d_in[4];
  const float* cWh = (const float*)d_in[5];  const float* cbh = (const float*)d_in[6];
  const float* cWs = (const float*)d_in[7];  const float* cbs = (const float*)d_in[8];
  const float* cWb = (const float*)d_in[9];  const float* cbb = (const float*)d_in[10];
  const float* cWd = (const float*)d_in[11]; const float* cbd = (const float*)d_in[12];
  const float* cWr = (const float*)d_in[13]; const float* cbr = (const float*)d_in[14];
  int iWm = 27, ibm = 28, ifb = 15;
  if (n_in > 15 && in_sizes[15] == 512){ iWm = 15; ibm = 16; ifb = 17; }
  const float* fW0 = (const float*)d_in[ifb+0];  const float* fb0 = (const float*)d_in[ifb+1];
  const float* fWh = (const float*)d_in[ifb+2];  const float* fbh = (const float*)d_in[ifb+3];
  const float* fWs = (const float*)d_in[ifb+4];  const float* fbs = (const float*)d_in[ifb+5];
  const float* fWb = (const float*)d_in[ifb+6];  const float* fbb = (const float*)d_in[ifb+7];
  const float* fWd = (const float*)d_in[ifb+8];  const float* fbd = (const float*)d_in[ifb+9];
  const float* fWr = (const float*)d_in[ifb+10]; const float* fbr = (const float*)d_in[ifb+11];
  const float* cWm = (const float*)d_in[iWm];    const float* cbm = (const float*)d_in[ibm];

  char* base = (char*)d_ws;
  size_t off = 0;
  auto alloc = [&](size_t bytes)->void*{ off = (off+63) & ~(size_t)63; void* p = base+off; off += bytes; return p; };

  float* tfine = (float*)alloc((size_t)NRAYS*129*4);
  f16 *cW0h=(f16*)alloc((size_t)256*128*2), *cW0l=(f16*)alloc((size_t)256*128*2);
  f16 *cWhh=(f16*)alloc((size_t)3*256*256*2), *cWhl=(f16*)alloc((size_t)3*256*256*2);
  f16 *cWbh=(f16*)alloc((size_t)256*256*2), *cWbl=(f16*)alloc((size_t)256*256*2);
  f16 *cWdh=(f16*)alloc((size_t)128*256*2), *cWdl=(f16*)alloc((size_t)128*256*2);
  f16 *fW0h=(f16*)alloc((size_t)256*128*2), *fW0l=(f16*)alloc((size_t)256*128*2);
  f16 *fWhh=(f16*)alloc((size_t)3*256*256*2), *fWhl=(f16*)alloc((size_t)3*256*256*2);
  f16 *fWbh=(f16*)alloc((size_t)256*256*2), *fWbl=(f16*)alloc((size_t)256*256*2);
  f16 *fWdh=(f16*)alloc((size_t)128*256*2), *fWdl=(f16*)alloc((size_t)128*256*2);

  // single fused conversion launch: 12 jobs, 256-thread blocks
  CvtJobs jobs;
  int bb = 0;
  auto addJob = [&](int idx, const float* src, f16* dh, f16* dl, int Ksrc, int N, int Kdst){
    jobs.j[idx] = { src, dh, dl, Ksrc, N, Kdst, bb };
    bb += (N*Kdst + 255)/256;
  };
  addJob(0,  cW0, cW0h, cW0l, 96, 256, 128);
  addJob(1,  cWh,            cWhh,          cWhl,          256, 256, 256);
  addJob(2,  cWh+65536,      cWhh+65536,    cWhl+65536,    256, 256, 256);
  addJob(3,  cWh+131072,     cWhh+131072,   cWhl+131072,   256, 256, 256);
  addJob(4,  cWb, cWbh, cWbl, 256, 256, 256);
  addJob(5,  cWd, cWdh, cWdl, 256, 128, 256);
  addJob(6,  fW0, fW0h, fW0l, 96, 256, 128);
  addJob(7,  fWh,            fWhh,          fWhl,          256, 256, 256);
  addJob(8,  fWh+65536,      fWhh+65536,    fWhl+65536,    256, 256, 256);
  addJob(9,  fWh+131072,     fWhh+131072,   fWhl+131072,   256, 256, 256);
  addJob(10, fWb, fWbh, fWbl, 256, 256, 256);
  addJob(11, fWd, fWdh, fWdl, 256, 128, 256);
  k_cvt_all<<<bb,256,0,stream>>>(jobs);

  Weights wc = { cW0h,cW0l,cb0, cWhh,cWhl,cbh, cWs,cbs,cWm,cbm,
                 cWbh,cWbl,cbb, cWdh,cWdl,cWd,cbd, cWr,cbr };
  Weights wf = { fW0h,fW0l,fb0, fWhh,fWhl,fbh, fWs,fbs,nullptr,nullptr,
                 fWbh,fWbl,fbb, fWdh,fWdl,fWd,fbd, fWr,fbr };

  k_coarse<<<NRAYS,1024,0,stream>>>(ro, rd, rr, wc, tfine, (float*)d_out);
  k_fine  <<<NRAYS,1024,0,stream>>>(ro, rd, rr, wf, tfine, (float*)d_out);
}

// Round 17
// 888.029 us; speedup vs baseline: 1.0486x; 1.0058x over previous
//
#include <hip/hip_runtime.h>

#define NRAYS 2048
// X stored in MFMA-fragment order: tile (m=row/16, kt=col/32) at ((m*8+kt)*512),
// within tile: lane-chunk (q=col%32/8)*16 + (r=row%16), 8 f16 per chunk (col%8).
#define XTILE(m,kt) ((((m)<<3)+(kt))<<9)
__device__ __forceinline__ int xaddr(int row, int col){
  return XTILE(row>>4, col>>5) + ((((col&31)>>3)<<4) + (row&15))*8 + (col&7);
}

typedef _Float16 f16;
typedef __attribute__((ext_vector_type(4))) _Float16 f16x4;
typedef __attribute__((ext_vector_type(8))) _Float16 f16x8;
typedef __attribute__((ext_vector_type(4))) float f32x4;

__device__ __forceinline__ float sigmoidf(float x){ return 1.f/(1.f+expf(-x)); }

__device__ __forceinline__ float approx_cdf_f(float x){
  return 0.5f*(1.f + tanhf(0.7978845608028654f*(x + 0.044715f*x*x*x)));
}

// Giles (2010) single-precision erfinv, max rel err ~1e-6
__device__ __forceinline__ float erfinvf_dev(float x){
  float w = -logf((1.0f-x)*(1.0f+x));
  float p;
  if (w < 5.0f){
    w -= 2.5f;
    p = 2.81022636e-08f;
    p = fmaf(p,w, 3.43273939e-07f);
    p = fmaf(p,w,-3.5233877e-06f);
    p = fmaf(p,w,-4.39150654e-06f);
    p = fmaf(p,w, 0.00021858087f);
    p = fmaf(p,w,-0.00125372503f);
    p = fmaf(p,w,-0.00417768164f);
    p = fmaf(p,w, 0.246640727f);
    p = fmaf(p,w, 1.50140941f);
  } else {
    w = sqrtf(w) - 3.0f;
    p = -0.000200214257f;
    p = fmaf(p,w, 0.000100950558f);
    p = fmaf(p,w, 0.00134934322f);
    p = fmaf(p,w,-0.00367342844f);
    p = fmaf(p,w, 0.00573950773f);
    p = fmaf(p,w,-0.0076224613f);
    p = fmaf(p,w, 0.00943887047f);
    p = fmaf(p,w, 1.00167406f);
    p = fmaf(p,w, 2.83297682f);
  }
  return p*x;
}

// ---------- fused weight convert: 12 jobs in one launch ----------
struct CvtJob { const float* src; f16* dh; f16* dl; int Ksrc, N, Kdst, blkBase; };
struct CvtJobs { CvtJob j[12]; };

__global__ void k_cvt_all(CvtJobs jobs){
  int b = blockIdx.x;
  int ji = 0;
  #pragma unroll
  for (int i=1;i<12;i++) if (b >= jobs.j[i].blkBase) ji = i;
  const CvtJob& J = jobs.j[ji];
  int g = (b - J.blkBase)*256 + threadIdx.x;
  if (g >= J.N*J.Kdst) return;
  int n = g / J.Kdst, k = g - n*J.Kdst;
  float v = (k < J.Ksrc) ? J.src[(size_t)k*J.N + n] : 0.f;
  f16 h = (f16)v;
  J.dh[g] = h;
  J.dl[g] = (f16)(v - (float)h);
}

struct Weights {
  const f16 *W0h,*W0l; const float *b0;
  const f16 *Whh,*Whl; const float *bh;
  const float *Ws,*bs,*Wm,*bm;      // Wm,bm only used by coarse
  const f16 *Wbh,*Wbl; const float *bb;
  const f16 *Wdh,*Wdl; const float *Wdfull,*bd;
  const float *Wr,*br;
};

// One layer: X(128 x K, fragment-order LDS) @ BT^T (N x K, L2) -> X.
// 16 waves; wave covers 16 output cols (waves with nbase>=N idle at barrier);
// 8 m-tiles -> acc[8]. PF=1 B-prefetch.
// TRANSPOSED MFMA: acc = mfma(Bfrag, Afrag) = C^T; lane (q,r) holds row m*16+r,
// cols nbase+q*4..+3 -> single b64 write into fragment layout.
// SPLIT: acc = Bh*Ah + Bl*Ah + Bh*Al (fp32-equivalent), writes h+l.
// !SPLIT: acc = Bh*Ah (pure f16), reads/writes h only.
template<int K, int N, bool SPLIT>
__device__ __forceinline__ void mlp_layer(
    f16* __restrict__ Xh, f16* __restrict__ Xl,
    const f16* __restrict__ Bh, const f16* __restrict__ Bl,
    const float* __restrict__ bias, const float* dctr, int relu,
    int wave, int q, int r, int lane)
{
  const int nbase = wave * 16;
  const bool act = (nbase < N);
  f32x4 acc[8];
  #pragma unroll
  for (int m=0;m<8;m++) acc[m] = (f32x4){0.f,0.f,0.f,0.f};
  if (act){
    const f16* bhp = Bh + (size_t)(nbase + r)*K + q*8;
    const f16* blp = Bl + (size_t)(nbase + r)*K + q*8;
    f16x8 bh = *(const f16x8*)bhp;
    f16x8 bl;
    if (SPLIT) bl = *(const f16x8*)blp;
    #pragma unroll
    for (int k0=0;k0<K;k0+=32){
      const int kt = k0 >> 5;
      f16x8 bh_n, bl_n;
      if (k0+32 < K){
        bh_n = *(const f16x8*)(bhp + k0 + 32);
        if (SPLIT) bl_n = *(const f16x8*)(blp + k0 + 32);
      }
      #pragma unroll
      for (int m=0;m<8;m++){
        int ao = XTILE(m,kt) + (lane<<3);
        f16x8 ah = *(const f16x8*)&Xh[ao];
        acc[m] = __builtin_amdgcn_mfma_f32_16x16x32_f16(bh, ah, acc[m], 0,0,0);
        if (SPLIT){
          f16x8 al = *(const f16x8*)&Xl[ao];
          acc[m] = __builtin_amdgcn_mfma_f32_16x16x32_f16(bl, ah, acc[m], 0,0,0);
          acc[m] = __builtin_amdgcn_mfma_f32_16x16x32_f16(bh, al, acc[m], 0,0,0);
        }
      }
      bh = bh_n;
      if (SPLIT) bl = bl_n;
    }
  }
  __syncthreads();   // all waves done reading X
  if (act){
    const int c0 = nbase + q*4;
    const int ktp = c0 >> 5, qp = (c0 & 31) >> 3, j0 = c0 & 7;
    float ba0=0.f,ba1=0.f,ba2=0.f,ba3=0.f;
    if (bias){ ba0=bias[c0]; ba1=bias[c0+1]; ba2=bias[c0+2]; ba3=bias[c0+3]; }
    if (dctr){ ba0+=dctr[c0]; ba1+=dctr[c0+1]; ba2+=dctr[c0+2]; ba3+=dctr[c0+3]; }
    #pragma unroll
    for (int m=0;m<8;m++){
      int ao = XTILE(m,ktp) + ((qp<<4) + r)*8 + j0;
      float v0 = acc[m][0] + ba0, v1 = acc[m][1] + ba1;
      float v2 = acc[m][2] + ba2, v3 = acc[m][3] + ba3;
      if (relu){ v0=fmaxf(v0,0.f); v1=fmaxf(v1,0.f); v2=fmaxf(v2,0.f); v3=fmaxf(v3,0.f); }
      f16 h0=(f16)v0, h1=(f16)v1, h2=(f16)v2, h3=(f16)v3;
      f16x4 hv = {h0,h1,h2,h3};
      *(f16x4*)&Xh[ao] = hv;
      if (SPLIT){
        f16x4 lv = {(f16)(v0-(float)h0),(f16)(v1-(float)h1),(f16)(v2-(float)h2),(f16)(v3-(float)h3)};
        *(f16x4*)&Xl[ao] = lv;
      }
    }
  }
  __syncthreads();
}

// shared enc math
__device__ __forceinline__ void enc_vals(
    float t0, float t1, float rrv,
    const float* rov, const float* rdv, float invdd,
    int j, int kk, float& a0, float& a1)
{
  float c = 0.5f*(t0+t1), d = 0.5f*(t1-t0);
  float c2 = c*c, d2 = d*d;
  float denom = 3.f*c2 + d2;
  float t_mean = c + 2.f*c*d2/denom;
  float d4 = d2*d2;
  float t_var = d2*(1.f/3.f) - (4.f/15.f)*(d4*(12.f*c2 - d2))/(denom*denom);
  float r_var = rrv*rrv*(c2*0.25f + (5.f/12.f)*d2 - (4.f/15.f)*d4/denom);
  float mean = rov[j] + rdv[j]*t_mean;
  float doj = rdv[j]*rdv[j];
  float cov = t_var*doj + r_var*(1.f - doj*invdd);
  float sc = (float)(1<<kk);
  float att = expf(-0.5f*cov*sc*sc);
  float sv, cv;
  sincosf(mean*sc, &sv, &cv);
  a0 = sv*att; a1 = cv*att;
}

// ---------- COARSE: enc + exact trunk + heads + lite rgb-path + render + sampling ----------
__global__ __launch_bounds__(1024,4) void k_coarse(
    const float* __restrict__ ro, const float* __restrict__ rd, const float* __restrict__ rr,
    Weights w, float* __restrict__ tfine_out, float* __restrict__ dout)
{
  __shared__ f16 Xh[32768];
  __shared__ f16 Xl[32768];
  __shared__ float sh_de[32];
  __shared__ float sh_dctr[128];
  __shared__ float sh_sig[128], sh_mu[128], sh_sgm[128];
  __shared__ float sh_rgb[3*128];
  __shared__ float red[16];
  __shared__ float sh_w[128], sh_pdf[128], sh_cdf[132], sh_lt[128], sh_pib[128];
  __shared__ float s_wsum;

  int ray = blockIdx.x, tid = threadIdx.x;
  int wave = tid>>6, lane = tid&63, q = lane>>4, r = lane&15;

  float rdx = rd[ray*3], rdy = rd[ray*3+1], rdz = rd[ray*3+2];
  float rn = sqrtf(rdx*rdx+rdy*rdy+rdz*rdz);

  if (tid < 27){
    float v0=rdx/rn, v1=rdy/rn, v2=rdz/rn;
    float vv[3] = {v0,v1,v2};
    float o;
    if (tid < 3) o = vv[tid];
    else if (tid < 15){ int f=(tid-3)/3, j=(tid-3)%3; o = sinf(vv[j]*(float)(1<<f)); }
    else            { int f=(tid-15)/3, j=(tid-15)%3; o = cosf(vv[j]*(float)(1<<f)); }
    sh_de[tid] = o;
  }

  // enc (h+l): sample s = tid>>3, part p = tid&7 handles freqs p*2..p*2+1
  {
    int s = tid >> 3, p = tid & 7;
    float t0 = 2.f + 0.03125f*(float)s, t1 = t0 + 0.03125f;
    float rrv = rr[ray];
    float rdv[3] = {rdx, rdy, rdz};
    float rov[3] = {ro[ray*3], ro[ray*3+1], ro[ray*3+2]};
    float dd = rdx*rdx+rdy*rdy+rdz*rdz;
    float invdd = 1.f/fmaxf(dd, 1e-10f);
    #pragma unroll
    for (int j=0;j<3;j++){
      #pragma unroll
      for (int kk=p*2; kk<p*2+2; kk++){
        float a0, a1;
        enc_vals(t0,t1,rrv,rov,rdv,invdd,j,kk,a0,a1);
        f16 h0=(f16)a0, h1=(f16)a1;
        int i0 = xaddr(s, kk*3 + j), i1 = xaddr(s, 48 + kk*3 + j);
        Xh[i0]=h0; Xl[i0]=(f16)(a0-(float)h0);
        Xh[i1]=h1; Xl[i1]=(f16)(a1-(float)h1);
      }
    }
    #pragma unroll
    for (int i=0;i<4;i++){
      int a = xaddr(s, 96 + p*4 + i);
      Xh[a]=(f16)0.f; Xl[a]=(f16)0.f;
    }
  }
  __syncthreads();

  if (tid < 128){
    float acc = w.bd[tid];
    #pragma unroll
    for (int k=0;k<27;k++) acc = fmaf(sh_de[k], w.Wdfull[(size_t)(256+k)*128 + tid], acc);
    sh_dctr[tid] = acc;
  }

  // ---- exact trunk (feeds the chaotic sampler) ----
  mlp_layer<128,256,true>(Xh,Xl, w.W0h, w.W0l, w.b0, nullptr, 1, wave,q,r,lane);
  mlp_layer<256,256,true>(Xh,Xl, w.Whh,          w.Whl,          w.bh,      nullptr, 1, wave,q,r,lane);
  mlp_layer<256,256,true>(Xh,Xl, w.Whh+65536,    w.Whl+65536,    w.bh+256,  nullptr, 1, wave,q,r,lane);
  mlp_layer<256,256,true>(Xh,Xl, w.Whh+131072,   w.Whl+131072,   w.bh+512,  nullptr, 1, wave,q,r,lane);

  // sigma/mu/sig heads (exact h+l reads): 8 lanes per row, cols p*32..p*32+31
  {
    int row = tid>>3, p = tid&7;
    int m = row>>4, rr_ = row&15;
    float s0=0.f, s1=0.f, s2=0.f;
    #pragma unroll
    for (int i=0;i<4;i++){
      int a = XTILE(m,p) + ((i<<4) + rr_)*8;
      f16x8 vh = *(const f16x8*)&Xh[a];
      f16x8 vl = *(const f16x8*)&Xl[a];
      #pragma unroll
      for (int e=0;e<8;e++){
        int k = p*32 + i*8 + e;
        float xv = (float)vh[e] + (float)vl[e];
        s0 = fmaf(xv, w.Ws[k], s0);
        s1 = fmaf(xv, w.Wm[2*k], s1);
        s2 = fmaf(xv, w.Wm[2*k+1], s2);
      }
    }
    s0 += __shfl_xor(s0,1); s0 += __shfl_xor(s0,2); s0 += __shfl_xor(s0,4);
    s1 += __shfl_xor(s1,1); s1 += __shfl_xor(s1,2); s1 += __shfl_xor(s1,4);
    s2 += __shfl_xor(s2,1); s2 += __shfl_xor(s2,2); s2 += __shfl_xor(s2,4);
    if (p==0){
      sh_sig[row] = s0 + w.bs[0];
      sh_mu[row]  = sigmoidf(s1 + w.bm[0]);
      sh_sgm[row] = 2.f*(sigmoidf(s2 + w.bm[1]) + 0.001f);
    }
  }

  // rgb path: lite single-MFMA (only affects rgb_c, which tolerates full f16)
  mlp_layer<256,256,false>(Xh,Xl, w.Wbh, w.Wbl, w.bb, nullptr, 0, wave,q,r,lane);
  mlp_layer<256,128,false>(Xh,Xl, w.Wdh, w.Wdl, nullptr, sh_dctr, 1, wave,q,r,lane);

  // rgb head (h-only reads): cols p*16..p*16+15
  {
    int row = tid>>3, p = tid&7;
    int m = row>>4, rr_ = row&15;
    int kt = p>>1, qb = (p&1)*2;
    float s0=0.f,s1=0.f,s2=0.f;
    #pragma unroll
    for (int i=0;i<2;i++){
      int a = XTILE(m,kt) + (((qb+i)<<4) + rr_)*8;
      f16x8 vh = *(const f16x8*)&Xh[a];
      #pragma unroll
      for (int e=0;e<8;e++){
        int k = p*16 + i*8 + e;
        float hv = (float)vh[e];
        s0 = fmaf(hv, w.Wr[3*k  ], s0);
        s1 = fmaf(hv, w.Wr[3*k+1], s1);
        s2 = fmaf(hv, w.Wr[3*k+2], s2);
      }
    }
    s0 += __shfl_xor(s0,1); s0 += __shfl_xor(s0,2); s0 += __shfl_xor(s0,4);
    s1 += __shfl_xor(s1,1); s1 += __shfl_xor(s1,2); s1 += __shfl_xor(s1,4);
    s2 += __shfl_xor(s2,1); s2 += __shfl_xor(s2,2); s2 += __shfl_xor(s2,4);
    if (p==0){
      sh_rgb[row*3  ] = s0 + w.br[0];
      sh_rgb[row*3+1] = s1 + w.br[1];
      sh_rgb[row*3+2] = s2 + w.br[2];
    }
  }
  __syncthreads();

  // ---- volume render + sampling ----
  float alpha = 0.f;
  if (tid < 128){
    float sg = fmaxf(sh_sig[tid], 0.f);
    alpha = 1.f - expf(-sg * (0.03125f*rn));
    float mu = sh_mu[tid], sm = sh_sgm[tid];
    float lt = approx_cdf_f((0.f-mu)/sm);
    sh_lt[tid] = lt;
    sh_pib[tid] = approx_cdf_f((1.f-mu)/sm) - lt;
  }
  float incl = 1.f;
  if (tid < 128){
    incl = 1.f - alpha + 1e-10f;
    #pragma unroll
    for (int off=1; off<64; off<<=1){
      float y = __shfl_up(incl, off);
      if (lane >= off) incl *= y;
    }
    if (lane == 63) red[8 + (tid>>6)] = incl;
  }
  __syncthreads();
  if (tid < 128){
    float basep = (tid >= 64) ? red[8] : 1.f;
    float prev = __shfl_up(incl, 1);
    float excl = (lane == 0) ? 1.f : prev;
    sh_w[tid] = alpha * excl * basep;
  }
  __syncthreads();

  {
    float a0=0.f,a1=0.f,a2=0.f,a3=0.f;
    if (tid < 128){
      float wv = sh_w[tid];
      a0 = wv*sigmoidf(sh_rgb[tid*3+0]);
      a1 = wv*sigmoidf(sh_rgb[tid*3+1]);
      a2 = wv*sigmoidf(sh_rgb[tid*3+2]);
      a3 = wv + 1e-5f;
      #pragma unroll
      for (int off=32; off>0; off>>=1){
        a0 += __shfl_down(a0,off); a1 += __shfl_down(a1,off);
        a2 += __shfl_down(a2,off); a3 += __shfl_down(a3,off);
      }
      if (lane == 0){
        int wv2 = tid>>6;
        red[wv2*4+0]=a0; red[wv2*4+1]=a1; red[wv2*4+2]=a2; red[wv2*4+3]=a3;
      }
    }
    __syncthreads();
    if (tid==0){
      dout[ray*3  ] = red[0]+red[4];
      dout[ray*3+1] = red[1]+red[5];
      dout[ray*3+2] = red[2]+red[6];
      s_wsum = red[3]+red[7];
    }
  }
  __syncthreads();

  float aincl = 0.f;
  if (tid < 128){
    sh_pdf[tid] = (sh_w[tid]+1e-5f)/s_wsum;
    aincl = sh_pdf[tid];
    #pragma unroll
    for (int off=1; off<64; off<<=1){
      float y = __shfl_up(aincl, off);
      if (lane >= off) aincl += y;
    }
    if (lane == 63) red[12 + (tid>>6)] = aincl;
  }
  __syncthreads();
  if (tid < 128){
    float addp = (tid >= 64) ? red[12] : 0.f;
    sh_cdf[tid+1] = aincl + addp;
    if (tid == 0) sh_cdf[0] = 0.f;
  }
  __syncthreads();

  if (tid < 129){
    float u = (float)tid * ((1.f-1e-5f)/128.f);
    int lo=0, hi=129;
    while (lo<hi){ int mid=(lo+hi)>>1; if (sh_cdf[mid] <= u) lo=mid+1; else hi=mid; }
    int idx = lo-1; idx = idx<0?0:(idx>127?127:idx);
    float frac = (u - sh_cdf[idx]) / fmaxf(sh_pdf[idx], 1e-10f);
    frac = fminf(fmaxf(frac,0.f),1.f);
    float p = sh_lt[idx] + frac*sh_pib[idx];
    p = fminf(fmaxf(p, 1e-5f), 1.f-1e-5f);
    float xx = sh_mu[idx] + sh_sgm[idx]*1.4142135623730951f*erfinvf_dev(2.f*p-1.f);
    xx = fminf(fmaxf(xx,0.f),1.f);
    float b0 = 2.f + 0.03125f*(float)idx;
    tfine_out[(size_t)ray*129+tid] = b0 + xx*0.03125f;
  }
}

// ---------- FINE: pure f16 (single MFMA per step); 2 blocks/CU ----------
__global__ __launch_bounds__(1024,8) void k_fine(
    const float* __restrict__ ro, const float* __restrict__ rd, const float* __restrict__ rr,
    Weights w, const float* __restrict__ tfine_in, float* __restrict__ dout)
{
  __shared__ f16 Xh[32768];
  __shared__ float sh_t[132];
  __shared__ float sh_de[32];
  __shared__ float sh_dctr[128];
  __shared__ float sh_sig[128];
  __shared__ float sh_rgb[3*128];
  __shared__ float red[16];
  __shared__ float sh_w[128];

  int ray = blockIdx.x, tid = threadIdx.x;
  int wave = tid>>6, lane = tid&63, q = lane>>4, r = lane&15;

  float rdx = rd[ray*3], rdy = rd[ray*3+1], rdz = rd[ray*3+2];
  float rn = sqrtf(rdx*rdx+rdy*rdy+rdz*rdz);

  if (tid <= 128) sh_t[tid] = tfine_in[(size_t)ray*129 + tid];
  if (tid < 27){
    float v0=rdx/rn, v1=rdy/rn, v2=rdz/rn;
    float vv[3] = {v0,v1,v2};
    float o;
    if (tid < 3) o = vv[tid];
    else if (tid < 15){ int f=(tid-3)/3, j=(tid-3)%3; o = sinf(vv[j]*(float)(1<<f)); }
    else            { int f=(tid-15)/3, j=(tid-15)%3; o = cosf(vv[j]*(float)(1<<f)); }
    sh_de[tid] = o;
  }
  __syncthreads();

  {
    int s = tid >> 3, p = tid & 7;
    float t0 = sh_t[s], t1 = sh_t[s+1];
    float rrv = rr[ray];
    float rdv[3] = {rdx, rdy, rdz};
    float rov[3] = {ro[ray*3], ro[ray*3+1], ro[ray*3+2]};
    float dd = rdx*rdx+rdy*rdy+rdz*rdz;
    float invdd = 1.f/fmaxf(dd, 1e-10f);
    #pragma unroll
    for (int j=0;j<3;j++){
      #pragma unroll
      for (int kk=p*2; kk<p*2+2; kk++){
        float a0, a1;
        enc_vals(t0,t1,rrv,rov,rdv,invdd,j,kk,a0,a1);
        Xh[xaddr(s, kk*3 + j)]      = (f16)a0;
        Xh[xaddr(s, 48 + kk*3 + j)] = (f16)a1;
      }
    }
    #pragma unroll
    for (int i=0;i<4;i++) Xh[xaddr(s, 96 + p*4 + i)] = (f16)0.f;
  }
  __syncthreads();

  if (tid < 128){
    float acc = w.bd[tid];
    #pragma unroll
    for (int k=0;k<27;k++) acc = fmaf(sh_de[k], w.Wdfull[(size_t)(256+k)*128 + tid], acc);
    sh_dctr[tid] = acc;
  }

  mlp_layer<128,256,false>(Xh,nullptr, w.W0h, w.W0l, w.b0, nullptr, 1, wave,q,r,lane);
  mlp_layer<256,256,false>(Xh,nullptr, w.Whh,          w.Whl,          w.bh,      nullptr, 1, wave,q,r,lane);
  mlp_layer<256,256,false>(Xh,nullptr, w.Whh+65536,    w.Whl+65536,    w.bh+256,  nullptr, 1, wave,q,r,lane);
  mlp_layer<256,256,false>(Xh,nullptr, w.Whh+131072,   w.Whl+131072,   w.bh+512,  nullptr, 1, wave,q,r,lane);

  // sigma head (h-only): cols p*32..p*32+31
  {
    int row = tid>>3, p = tid&7;
    int m = row>>4, rr_ = row&15;
    float s0=0.f;
    #pragma unroll
    for (int i=0;i<4;i++){
      int a = XTILE(m,p) + ((i<<4) + rr_)*8;
      f16x8 vh = *(const f16x8*)&Xh[a];
      #pragma unroll
      for (int e=0;e<8;e++) s0 = fmaf((float)vh[e], w.Ws[p*32+i*8+e], s0);
    }
    s0 += __shfl_xor(s0,1); s0 += __shfl_xor(s0,2); s0 += __shfl_xor(s0,4);
    if (p==0) sh_sig[row] = s0 + w.bs[0];
  }

  mlp_layer<256,256,false>(Xh,nullptr, w.Wbh, w.Wbl, w.bb, nullptr, 0, wave,q,r,lane);
  mlp_layer<256,128,false>(Xh,nullptr, w.Wdh, w.Wdl, nullptr, sh_dctr, 1, wave,q,r,lane);

  // rgb head: cols p*16..p*16+15
  {
    int row = tid>>3, p = tid&7;
    int m = row>>4, rr_ = row&15;
    int kt = p>>1, qb = (p&1)*2;
    float s0=0.f,s1=0.f,s2=0.f;
    #pragma unroll
    for (int i=0;i<2;i++){
      int a = XTILE(m,kt) + (((qb+i)<<4) + rr_)*8;
      f16x8 vh = *(const f16x8*)&Xh[a];
      #pragma unroll
      for (int e=0;e<8;e++){
        int k = p*16 + i*8 + e;
        float hv = (float)vh[e];
        s0 = fmaf(hv, w.Wr[3*k  ], s0);
        s1 = fmaf(hv, w.Wr[3*k+1], s1);
        s2 = fmaf(hv, w.Wr[3*k+2], s2);
      }
    }
    s0 += __shfl_xor(s0,1); s0 += __shfl_xor(s0,2); s0 += __shfl_xor(s0,4);
    s1 += __shfl_xor(s1,1); s1 += __shfl_xor(s1,2); s1 += __shfl_xor(s1,4);
    s2 += __shfl_xor(s2,1); s2 += __shfl_xor(s2,2); s2 += __shfl_xor(s2,4);
    if (p==0){
      sh_rgb[row*3  ] = s0 + w.br[0];
      sh_rgb[row*3+1] = s1 + w.br[1];
      sh_rgb[row*3+2] = s2 + w.br[2];
    }
  }
  __syncthreads();

  float alpha = 0.f;
  if (tid < 128){
    float sg = fmaxf(sh_sig[tid], 0.f);
    alpha = 1.f - expf(-sg*(sh_t[tid+1]-sh_t[tid])*rn);
  }
  float incl = 1.f;
  if (tid < 128){
    incl = 1.f - alpha + 1e-10f;
    #pragma unroll
    for (int off=1; off<64; off<<=1){
      float y = __shfl_up(incl, off);
      if (lane >= off) incl *= y;
    }
    if (lane == 63) red[8 + (tid>>6)] = incl;
  }
  __syncthreads();
  if (tid < 128){
    float basep = (tid >= 64) ? red[8] : 1.f;
    float prev = __shfl_up(incl, 1);
    float excl = (lane == 0) ? 1.f : prev;
    sh_w[tid] = alpha * excl * basep;
  }
  __syncthreads();

  {
    float a0=0.f,a1=0.f,a2=0.f,a3=0.f,a4=0.f;
    if (tid < 128){
      float wv = sh_w[tid];
      a0 = wv*sigmoidf(sh_rgb[tid*3+0]);
      a1 = wv*sigmoidf(sh_rgb[tid*3+1]);
      a2 = wv*sigmoidf(sh_rgb[tid*3+2]);
      a3 = wv*0.5f*(sh_t[tid]+sh_t[tid+1]);
      a4 = wv;
      #pragma unroll
      for (int off=32; off>0; off>>=1){
        a0 += __shfl_down(a0,off); a1 += __shfl_down(a1,off);
        a2 += __shfl_down(a2,off); a3 += __shfl_down(a3,off);
        a4 += __shfl_down(a4,off);
      }
      if (lane == 0){
        int wv2 = tid>>6;
        red[wv2*5+0]=a0; red[wv2*5+1]=a1; red[wv2*5+2]=a2; red[wv2*5+3]=a3; red[wv2*5+4]=a4;
      }
    }
    __syncthreads();
    if (tid==0){
      dout[NRAYS*3 + ray*3  ] = red[0]+red[5];
      dout[NRAYS*3 + ray*3+1] = red[1]+red[6];
      dout[NRAYS*3 + ray*3+2] = red[2]+red[7];
      dout[NRAYS*6 + ray] = red[3]+red[8];
      dout[NRAYS*7 + ray] = red[4]+red[9];
    }
  }
}

extern "C" void kernel_launch(void* const* d_in, const int* in_sizes, int n_in,
                              void* d_out, int out_size, void* d_ws, size_t ws_size,
                              hipStream_t stream) {
  const float* ro  = (const float*)d_in[0];
  const float* rd  = (const float*)d_in[1];
  const float* rr  = (const float*)d_in[2];
  const float* cW0 = (const float*)d_in[3];  const float* cb0 = (const float*)d_in[4];
  const float* cWh = (const float*)d_in[5];  const float* cbh = (const float*)d_in[6];
  const float* cWs = (const float*)d_in[7];  const float* cbs = (const float*)d_in[8];
  const float* cWb = (const float*)d_in[9];  const float* cbb = (const float*)d_in[10];
  const float* cWd = (const float*)d_in[11]; const float* cbd = (const float*)d_in[12];
  const float* cWr = (const float*)d_in[13]; const float* cbr = (const float*)d_in[14];
  int iWm = 27, ibm = 28, ifb = 15;
  if (n_in > 15 && in_sizes[15] == 512){ iWm = 15; ibm = 16; ifb = 17; }
  const float* fW0 = (const float*)d_in[ifb+0];  const float* fb0 = (const float*)d_in[ifb+1];
  const float* fWh = (const float*)d_in[ifb+2];  const float* fbh = (const float*)d_in[ifb+3];
  const float* fWs = (const float*)d_in[ifb+4];  const float* fbs = (const float*)d_in[ifb+5];
  const float* fWb = (const float*)d_in[ifb+6];  const float* fbb = (const float*)d_in[ifb+7];
  const float* fWd = (const float*)d_in[ifb+8];  const float* fbd = (const float*)d_in[ifb+9];
  const float* fWr = (const float*)d_in[ifb+10]; const float* fbr = (const float*)d_in[ifb+11];
  const float* cWm = (const float*)d_in[iWm];    const float* cbm = (const float*)d_in[ibm];

  char* base = (char*)d_ws;
  size_t off = 0;
  auto alloc = [&](size_t bytes)->void*{ off = (off+63) & ~(size_t)63; void* p = base+off; off += bytes; return p; };

  float* tfine = (float*)alloc((size_t)NRAYS*129*4);
  f16 *cW0h=(f16*)alloc((size_t)256*128*2), *cW0l=(f16*)alloc((size_t)256*128*2);
  f16 *cWhh=(f16*)alloc((size_t)3*256*256*2), *cWhl=(f16*)alloc((size_t)3*256*256*2);
  f16 *cWbh=(f16*)alloc((size_t)256*256*2), *cWbl=(f16*)alloc((size_t)256*256*2);
  f16 *cWdh=(f16*)alloc((size_t)128*256*2), *cWdl=(f16*)alloc((size_t)128*256*2);
  f16 *fW0h=(f16*)alloc((size_t)256*128*2), *fW0l=(f16*)alloc((size_t)256*128*2);
  f16 *fWhh=(f16*)alloc((size_t)3*256*256*2), *fWhl=(f16*)alloc((size_t)3*256*256*2);
  f16 *fWbh=(f16*)alloc((size_t)256*256*2), *fWbl=(f16*)alloc((size_t)256*256*2);
  f16 *fWdh=(f16*)alloc((size_t)128*256*2), *fWdl=(f16*)alloc((size_t)128*256*2);

  // single fused conversion launch: 12 jobs, 256-thread blocks
  CvtJobs jobs;
  int bb = 0;
  auto addJob = [&](int idx, const float* src, f16* dh, f16* dl, int Ksrc, int N, int Kdst){
    jobs.j[idx] = { src, dh, dl, Ksrc, N, Kdst, bb };
    bb += (N*Kdst + 255)/256;
  };
  addJob(0,  cW0, cW0h, cW0l, 96, 256, 128);
  addJob(1,  cWh,            cWhh,          cWhl,          256, 256, 256);
  addJob(2,  cWh+65536,      cWhh+65536,    cWhl+65536,    256, 256, 256);
  addJob(3,  cWh+131072,     cWhh+131072,   cWhl+131072,   256, 256, 256);
  addJob(4,  cWb, cWbh, cWbl, 256, 256, 256);
  addJob(5,  cWd, cWdh, cWdl, 256, 128, 256);
  addJob(6,  fW0, fW0h, fW0l, 96, 256, 128);
  addJob(7,  fWh,            fWhh,          fWhl,          256, 256, 256);
  addJob(8,  fWh+65536,      fWhh+65536,    fWhl+65536,    256, 256, 256);
  addJob(9,  fWh+131072,     fWhh+131072,   fWhl+131072,   256, 256, 256);
  addJob(10, fWb, fWbh, fWbl, 256, 256, 256);
  addJob(11, fWd, fWdh, fWdl, 256, 128, 256);
  k_cvt_all<<<bb,256,0,stream>>>(jobs);

  Weights wc = { cW0h,cW0l,cb0, cWhh,cWhl,cbh, cWs,cbs,cWm,cbm,
                 cWbh,cWbl,cbb, cWdh,cWdl,cWd,cbd, cWr,cbr };
  Weights wf = { fW0h,fW0l,fb0, fWhh,fWhl,fbh, fWs,fbs,nullptr,nullptr,
                 fWbh,fWbl,fbb, fWdh,fWdl,fWd,fbd, fWr,fbr };

  k_coarse<<<NRAYS,1024,0,stream>>>(ro, rd, rr, wc, tfine, (float*)d_out);
  k_fine  <<<NRAYS,1024,0,stream>>>(ro, rd, rr, wf, tfine, (float*)d_out);
}